// Round 1
// 741.925 us; speedup vs baseline: 1.0549x; 1.0549x over previous
//
#include <hip/hip_runtime.h>

typedef unsigned int uint;
typedef unsigned short ushort;

typedef _Float16 half8 __attribute__((ext_vector_type(8)));
typedef float f32x4 __attribute__((ext_vector_type(4)));

#define DEV __device__ __forceinline__

DEV ushort f2h(float x) {
    _Float16 h = (_Float16)x;
    ushort u;
    __builtin_memcpy(&u, &h, 2);
    return u;
}

// ---------------------------------------------------------------------------
// conv1: direct fp32 VALU (IC=1, K too small for MFMA). One thread per output
// pixel, 16 oc in registers. Output y1: NHWC f16. Fused BN stats.
// ---------------------------------------------------------------------------
__global__ __launch_bounds__(256, 2) void conv1_k(
    const float* __restrict__ x, const float* __restrict__ w,
    const float* __restrict__ bias, ushort* __restrict__ y1,
    float* __restrict__ sums)
{
    int idx = blockIdx.x * 256 + threadIdx.x;
    int ow = idx % 56;
    int oh = (idx / 56) % 56;
    int n  = idx / 3136;

    float acc[16];
#pragma unroll
    for (int o = 0; o < 16; ++o) acc[o] = bias[o];

    const float* xp = x + (size_t)n * 12544;
#pragma unroll
    for (int kh = 0; kh < 4; ++kh) {
        int ih = oh * 2 - 1 + kh;
        if ((uint)ih >= 112u) continue;
#pragma unroll
        for (int kw = 0; kw < 4; ++kw) {
            int iw = ow * 2 - 1 + kw;
            if ((uint)iw >= 112u) continue;
            float v = xp[ih * 112 + iw];
#pragma unroll
            for (int o = 0; o < 16; ++o)
                acc[o] = fmaf(v, w[o * 16 + kh * 4 + kw], acc[o]);
        }
    }

    ushort hs[16];
#pragma unroll
    for (int o = 0; o < 16; ++o) hs[o] = f2h(acc[o]);
    __builtin_memcpy(y1 + (size_t)idx * 16, hs, 32);

    // fused BN stats
    __shared__ float red[2][4][16];
    int lane = threadIdx.x & 63, wv = threadIdx.x >> 6;
#pragma unroll
    for (int o = 0; o < 16; ++o) {
        float s = acc[o], q = acc[o] * acc[o];
#pragma unroll
        for (int off = 32; off; off >>= 1) {
            s += __shfl_down(s, off);
            q += __shfl_down(q, off);
        }
        if (lane == 0) { red[0][wv][o] = s; red[1][wv][o] = q; }
    }
    __syncthreads();
    float* sl = sums + (blockIdx.x & 7) * 256;
    int t = threadIdx.x;
    if (t < 16)
        atomicAdd(&sl[t], red[0][0][t] + red[0][1][t] + red[0][2][t] + red[0][3][t]);
    else if (t >= 64 && t < 80) {
        int o = t - 64;
        atomicAdd(&sl[128 + o], red[1][0][o] + red[1][1][o] + red[1][2][o] + red[1][3][o]);
    }
}

// sums (8 slots x 256) -> (a, b) fold:  h = relu(a*y + b)
__global__ __launch_bounds__(128) void mkab(const float* __restrict__ sums,
                                            const float* __restrict__ g,
                                            const float* __restrict__ be,
                                            float* __restrict__ ab, int C, float invP)
{
    int c = threadIdx.x;
    if (c >= C) return;
    float s = 0.f, q = 0.f;
#pragma unroll
    for (int k = 0; k < 8; ++k) { s += sums[k * 256 + c]; q += sums[k * 256 + 128 + c]; }
    float mu  = s * invP;
    float var = fmaf(-mu, mu, q * invP);
    float a   = g[c] / sqrtf(var + 1e-5f);
    ab[c]     = a;
    ab[C + c] = fmaf(-mu, a, be[c]);
}

// Elementwise fold: h = f16(relu(a*y + b)), NHWC, C = power of 2.
template <int C>
__global__ __launch_bounds__(256) void fold(const ushort* __restrict__ y,
                                            const float* __restrict__ ab,
                                            ushort* __restrict__ h)
{
    __shared__ float sa[C], sb[C];
    if (threadIdx.x < C) { sa[threadIdx.x] = ab[threadIdx.x]; sb[threadIdx.x] = ab[C + threadIdx.x]; }
    __syncthreads();
    int idx = blockIdx.x * 256 + threadIdx.x;
    half8 v;
    __builtin_memcpy(&v, y + (size_t)idx * 8, 16);
    int c0 = (idx * 8) & (C - 1);
    half8 o;
#pragma unroll
    for (int e = 0; e < 8; ++e) {
        float f = (float)v[e];
        o[e] = (_Float16)fmaxf(fmaf(sa[c0 + e], f, sb[c0 + e]), 0.f);
    }
    __builtin_memcpy(h + (size_t)idx * 8, &o, 16);
}

// Repack conv weights OIHW fp32 -> [oc][kh][kw][ic] f16.
template <int OC, int IC, int K>
__global__ __launch_bounds__(256) void repack(const float* __restrict__ w,
                                              ushort* __restrict__ wb)
{
    int i = blockIdx.x * 256 + threadIdx.x;
    int ic = i % IC;
    int r  = i / IC;
    int kw = r % K;  r /= K;
    int kh = r % K;
    int oc = r / K;
    wb[i] = f2h(w[((oc * IC + ic) * K + kh) * K + kw]);
}

// ---------------------------------------------------------------------------
// conv2: implicit GEMM, K=4 S=2 P=1, IC=16 OC=32, in (512,56,56,16) f16 NHWC.
// Chunk = (kh, kw-pair): k = kwoff*16 + ic (32 wide). Masked A loads (padding).
// Block: 4 waves x 32 m-rows = 128 m. M = 512*784 = 401408 = 3136*128.
// ---------------------------------------------------------------------------
__global__ __launch_bounds__(256, 2) void conv2_mfma(
    const ushort* __restrict__ hin, const ushort* __restrict__ wb,
    const float* __restrict__ bias, ushort* __restrict__ y,
    float* __restrict__ sums)
{
    const int lane = threadIdx.x & 63, wv = threadIdx.x >> 6;
    const int col = lane & 15, quad = lane >> 4;
    const int kwoff = quad >> 1;
    const int icoff = (quad & 1) * 8;
    const int mbase = blockIdx.x * 128 + wv * 32;

    int nb[2], ihb[2], iwb[2];
#pragma unroll
    for (int s = 0; s < 2; ++s) {
        int m = mbase + s * 16 + col;
        int n = m / 784, rem = m % 784;
        int oh = rem / 28, ow = rem % 28;
        nb[s]  = n * 50176 + icoff;   // n*IH*IW*IC + ic offset (halfs)
        ihb[s] = oh * 2 - 1;
        iwb[s] = ow * 2 - 1 + kwoff;
    }

    float bv[2];
#pragma unroll
    for (int t = 0; t < 2; ++t) bv[t] = bias[t * 16 + col];

    f32x4 acc[2][2];
#pragma unroll
    for (int s = 0; s < 2; ++s)
#pragma unroll
        for (int t = 0; t < 2; ++t) acc[s][t] = (f32x4){0.f, 0.f, 0.f, 0.f};

    const int wrow = col * 256 + icoff;  // oc*K*K*IC + icoff

#pragma unroll
    for (int kh = 0; kh < 4; ++kh) {
#pragma unroll
        for (int kwp = 0; kwp < 2; ++kwp) {
            half8 af[2];
#pragma unroll
            for (int s = 0; s < 2; ++s) {
                int ih = ihb[s] + kh;
                int iw = iwb[s] + kwp * 2;
                uint r0 = 0, r1 = 0, r2 = 0, r3 = 0;
                if ((uint)ih < 56u && (uint)iw < 56u) {
                    uint raw[4];
                    __builtin_memcpy(raw, hin + nb[s] + ih * 896 + iw * 16, 16);
                    r0 = raw[0]; r1 = raw[1]; r2 = raw[2]; r3 = raw[3];
                }
                uint raw2[4] = {r0, r1, r2, r3};
                __builtin_memcpy(&af[s], raw2, 16);
            }
            const int boff = (kh * 4 + kwp * 2 + kwoff) * 16;
#pragma unroll
            for (int t = 0; t < 2; ++t) {
                half8 bf;
                __builtin_memcpy(&bf, wb + wrow + t * 4096 + boff, 16);
#pragma unroll
                for (int s = 0; s < 2; ++s)
                    acc[s][t] = __builtin_amdgcn_mfma_f32_16x16x32_f16(af[s], bf, acc[s][t], 0, 0, 0);
            }
        }
    }

    // epilogue: bias, f16 store (NHWC), fused stats
    float ss[2] = {0.f, 0.f}, qq[2] = {0.f, 0.f};
#pragma unroll
    for (int s = 0; s < 2; ++s) {
        int m0 = mbase + s * 16 + quad * 4;
#pragma unroll
        for (int t = 0; t < 2; ++t) {
#pragma unroll
            for (int r = 0; r < 4; ++r) {
                float yv = acc[s][t][r] + bv[t];
                ss[t] += yv;
                qq[t] = fmaf(yv, yv, qq[t]);
                y[(size_t)(m0 + r) * 32 + t * 16 + col] = f2h(yv);
            }
        }
    }
    __shared__ float redS[4][32], redQ[4][32];
#pragma unroll
    for (int t = 0; t < 2; ++t) {
        float s = ss[t], q = qq[t];
        s += __shfl_xor(s, 16); s += __shfl_xor(s, 32);
        q += __shfl_xor(q, 16); q += __shfl_xor(q, 32);
        if (quad == 0) { redS[wv][t * 16 + col] = s; redQ[wv][t * 16 + col] = q; }
    }
    __syncthreads();
    int t0 = threadIdx.x;
    float* sl = sums + (blockIdx.x & 7) * 256;
    if (t0 < 32)
        atomicAdd(&sl[t0], redS[0][t0] + redS[1][t0] + redS[2][t0] + redS[3][t0]);
    else if (t0 >= 128 && t0 < 160) {
        int c = t0 - 128;
        atomicAdd(&sl[128 + c], redQ[0][c] + redQ[1][c] + redQ[2][c] + redQ[3][c]);
    }
}

// ---------------------------------------------------------------------------
// conv3/conv4 (K=3, S=1, P=0): implicit GEMM with one-shot LDS staging of the
// A slab. Key fact: an m-contiguous block of 128 output pixels needs a
// CONTIGUOUS linear row range of NHWC input (rowlin = n*IH + oh), even across
// image boundaries. Max span = 10 rows. Stage once via global_load_lds
// (linear LDS dest, XOR-swizzled global source; read side applies the same
// involution byte ^= ((byte>>7)&7)<<4 to kill the stride-128B bank conflict).
// B (weights) stream from L2, register-double-buffered one chunk ahead so
// their latency hides under the MFMAs.
// ---------------------------------------------------------------------------
template <int IC, int OC, int K, int IH, int IW, int OH, int OW>
__global__ __launch_bounds__(256, 2) void conv_lds(
    const ushort* __restrict__ hin, const ushort* __restrict__ wb,
    const float* __restrict__ bias, ushort* __restrict__ y,
    float* __restrict__ sums)
{
    constexpr int NT  = OC / 16, NC = IC / 32;
    constexpr int KIC = K * K * IC, NCH = K * K * NC;
    constexpr int ROWB = IW * IC * 2;                         // bytes / input row
    constexpr int SLAB = ((10 * ROWB + 4095) / 4096) * 4096;  // padded LDS bytes
    __shared__ ushort slab[SLAB / 2];
    __shared__ float redS[4][OC], redQ[4][OC];

    const int lane = threadIdx.x & 63, wv = threadIdx.x >> 6;
    const int col = lane & 15, quad = lane >> 4;
    const int mbase = blockIdx.x * 128 + wv * 32;

    // block input row range (linear rows, contiguous even across images)
    const int m0  = blockIdx.x * 128;
    const int rl0 = (m0 / (OH * OW)) * IH + (m0 % (OH * OW)) / OW;
    const int mL  = m0 + 127;
    const int rl1 = (mL / (OH * OW)) * IH + (mL % (OH * OW)) / OW + (K - 1);
    const int stage_bytes = (rl1 - rl0 + 1) * ROWB;

    // stage A slab: linear LDS dest, pre-swizzled global source
    {
        const char* src = (const char*)(hin + (size_t)rl0 * (IW * IC));
        char* dst = (char*)slab;
        int d = threadIdx.x * 16;
        int rounds = (stage_bytes + 4095) >> 12;
        for (int r = 0; r < rounds; ++r) {
            int sw = d ^ (((d >> 7) & 7) << 4);
            __builtin_amdgcn_global_load_lds(
                (const __attribute__((address_space(1))) void*)(src + sw),
                (__attribute__((address_space(3))) void*)(dst + d), 16, 0, 0);
            d += 4096;
        }
    }

    // per-lane A base offset in halfs (pre-swizzle, relative to slab)
    int aloc[2];
#pragma unroll
    for (int s = 0; s < 2; ++s) {
        int m = mbase + s * 16 + col;
        int n = m / (OH * OW), rem = m % (OH * OW);
        int oh = rem / OW, ow = rem % OW;
        aloc[s] = ((n * IH + oh - rl0) * IW + ow) * IC + quad * 8;
    }
    const int wrow = col * KIC + quad * 8;

    float bv[NT];
#pragma unroll
    for (int t = 0; t < NT; ++t) bv[t] = bias[t * 16 + col];

    f32x4 acc[2][NT];
#pragma unroll
    for (int s = 0; s < 2; ++s)
#pragma unroll
        for (int t = 0; t < NT; ++t) acc[s][t] = (f32x4){0.f, 0.f, 0.f, 0.f};

    // prologue B load (chunk 0) — independent of LDS, overlaps the stage drain
    half8 bbuf[2][NT];
#pragma unroll
    for (int t = 0; t < NT; ++t)
        __builtin_memcpy(&bbuf[0][t], wb + wrow + t * 16 * KIC, 16);

    __syncthreads();   // drains vmcnt(0): slab (and chunk-0 B) complete

#pragma unroll
    for (int q = 0; q < NCH; ++q) {
        // prefetch next chunk's B into the other register buffer
        if (q + 1 < NCH) {
            const int q2 = q + 1;
            const int kidx2 = ((q2 / (K * NC)) * K + (q2 / NC) % K) * IC + (q2 % NC) * 32;
#pragma unroll
            for (int t = 0; t < NT; ++t)
                __builtin_memcpy(&bbuf[q2 & 1][t], wb + wrow + t * 16 * KIC + kidx2, 16);
        }
        const int kh = q / (K * NC), kw = (q / NC) % K, c = q % NC;
        const int aoff = (kh * IW + kw) * IC + c * 32;
        half8 af[2];
#pragma unroll
        for (int s = 0; s < 2; ++s) {
            int b = 2 * (aloc[s] + aoff);
            b ^= ((b >> 7) & 7) << 4;            // same involution as stage
            __builtin_memcpy(&af[s], (const char*)slab + b, 16);
        }
#pragma unroll
        for (int t = 0; t < NT; ++t)
#pragma unroll
            for (int s = 0; s < 2; ++s)
                acc[s][t] = __builtin_amdgcn_mfma_f32_16x16x32_f16(af[s], bbuf[q & 1][t], acc[s][t], 0, 0, 0);
    }

    // epilogue: bias, f16 store (NHWC), fused stats
    float ss[NT], qq[NT];
#pragma unroll
    for (int t = 0; t < NT; ++t) { ss[t] = 0.f; qq[t] = 0.f; }
#pragma unroll
    for (int s = 0; s < 2; ++s) {
        int me = mbase + s * 16 + quad * 4;
#pragma unroll
        for (int t = 0; t < NT; ++t) {
#pragma unroll
            for (int r = 0; r < 4; ++r) {
                float yv = acc[s][t][r] + bv[t];
                ss[t] += yv;
                qq[t] = fmaf(yv, yv, qq[t]);
                y[(size_t)(me + r) * OC + t * 16 + col] = f2h(yv);
            }
        }
    }
#pragma unroll
    for (int t = 0; t < NT; ++t) {
        float s = ss[t], q = qq[t];
        s += __shfl_xor(s, 16); s += __shfl_xor(s, 32);
        q += __shfl_xor(q, 16); q += __shfl_xor(q, 32);
        if (quad == 0) { redS[wv][t * 16 + col] = s; redQ[wv][t * 16 + col] = q; }
    }
    __syncthreads();
    int t0 = threadIdx.x;
    float* sl = sums + (blockIdx.x & 7) * 256;
    if (t0 < OC)
        atomicAdd(&sl[t0], redS[0][t0] + redS[1][t0] + redS[2][t0] + redS[3][t0]);
    else if (t0 >= 128 && t0 < 128 + OC) {
        int c = t0 - 128;
        atomicAdd(&sl[128 + c], redQ[0][c] + redQ[1][c] + redQ[2][c] + redQ[3][c]);
    }
}

// Global average pool over y4 (512,24,24,128) f16 NHWC, BN4+ReLU applied.
__global__ __launch_bounds__(256) void pool(const ushort* __restrict__ y4,
                                            const float* __restrict__ ab,
                                            float* __restrict__ f)
{
    int n = blockIdx.x;
    int c = threadIdx.x & 127, ph = threadIdx.x >> 7;
    const ushort* p = y4 + (size_t)n * 73728 + c;
    float a = ab[c], b = ab[128 + c];
    float s = 0.f;
    for (int i = ph * 288; i < ph * 288 + 288; ++i) {
        _Float16 hv;
        __builtin_memcpy(&hv, p + i * 128, 2);
        s += fmaxf(fmaf(a, (float)hv, b), 0.f);
    }
    __shared__ float l[128];
    if (ph == 1) l[c] = s;
    __syncthreads();
    if (ph == 0) f[n * 128 + c] = (s + l[c]) * (1.f / 576.f);
}

// L2-normalize feature rows, emit f16.
__global__ __launch_bounds__(128) void fnorm(const float* __restrict__ f,
                                             ushort* __restrict__ fnh)
{
    int n = blockIdx.x, t = threadIdx.x;
    float v = f[n * 128 + t];
    float q = v * v;
    for (int off = 32; off; off >>= 1) q += __shfl_down(q, off);
    __shared__ float l[2];
    if ((t & 63) == 0) l[t >> 6] = q;
    __syncthreads();
    float inv = 1.f / fmaxf(sqrtf(l[0] + l[1]), 1e-12f);
    fnh[n * 128 + t] = f2h(v * inv);
}

// arc_w row inverse norms. One wave per row.
__global__ __launch_bounds__(256) void wnorm(const float* __restrict__ w,
                                             float* __restrict__ winv)
{
    int wv = threadIdx.x >> 6, lane = threadIdx.x & 63;
    int j = blockIdx.x * 4 + wv;
    const float* p = w + (size_t)j * 128;
    float v0 = p[lane], v1 = p[lane + 64];
    float q = fmaf(v0, v0, v1 * v1);
    for (int off = 32; off; off >>= 1) q += __shfl_down(q, off);
    if (lane == 0) winv[j] = 1.f / fmaxf(sqrtf(q), 1e-12f);
}

// ---------------------------------------------------------------------------
// Final GEMM: out[i][j] = 64 * (fn[i] . wn[j]), margin fix at j == gt[i].
// M=512, N=100000, K=128. f16 MFMA 16x16x32, fp32 accumulate.
// ---------------------------------------------------------------------------
__global__ __launch_bounds__(256) void arc_gemm(const ushort* __restrict__ fnh,
                                                const float* __restrict__ aw,
                                                const float* __restrict__ winv,
                                                const int* __restrict__ gt,
                                                float* __restrict__ out)
{
    const int lane = threadIdx.x & 63, wv = threadIdx.x >> 6;
    const int col = lane & 15, quad = lane >> 4;
    const int j = blockIdx.x * 64 + wv * 16 + col;
    const bool jvalid = (j < 100000);
    const int jc = jvalid ? j : 99999;

    const float wi = winv[jc];
    const float* wp = aw + (size_t)jc * 128 + quad * 8;
    half8 bfr[4];
#pragma unroll
    for (int s = 0; s < 4; ++s) {
        half8 t;
#pragma unroll
        for (int e = 0; e < 8; ++e) t[e] = (_Float16)(wp[s * 32 + e] * wi);
        bfr[s] = t;
    }

    const float cm = 0.87758256189037272f;  // cos(0.5)
    const float sm = 0.47942553860420301f;  // sin(0.5)

    for (int mt = 0; mt < 32; ++mt) {
        const ushort* ap = fnh + (size_t)(mt * 16 + col) * 128 + quad * 8;
        f32x4 acc = {0.f, 0.f, 0.f, 0.f};
#pragma unroll
        for (int s = 0; s < 4; ++s) {
            half8 af;
            __builtin_memcpy(&af, ap + s * 32, 16);
            acc = __builtin_amdgcn_mfma_f32_16x16x32_f16(af, bfr[s], acc, 0, 0, 0);
        }
#pragma unroll
        for (int r = 0; r < 4; ++r) {
            int row = mt * 16 + quad * 4 + r;
            float v = acc[r];
            float o = 64.f * v;
            if (gt[row] == j) {
                float t = fmaxf(1.f - v * v, 0.f);
                o = 64.f * fmaf(v, cm, -sqrtf(t) * sm);
            }
            if (jvalid) out[(size_t)row * 100000 + j] = o;
        }
    }
}

// ---------------------------------------------------------------------------
extern "C" void kernel_launch(void* const* d_in, const int* in_sizes, int n_in,
                              void* d_out, int out_size, void* d_ws, size_t ws_size,
                              hipStream_t stream)
{
    const float* x   = (const float*)d_in[0];
    const int*   gt  = (const int*)d_in[1];
    const float* w1  = (const float*)d_in[2];
    const float* b1  = (const float*)d_in[3];
    const float* g1  = (const float*)d_in[4];
    const float* be1 = (const float*)d_in[5];
    const float* w2  = (const float*)d_in[6];
    const float* b2  = (const float*)d_in[7];
    const float* g2  = (const float*)d_in[8];
    const float* be2 = (const float*)d_in[9];
    const float* w3  = (const float*)d_in[10];
    const float* b3  = (const float*)d_in[11];
    const float* g3  = (const float*)d_in[12];
    const float* be3 = (const float*)d_in[13];
    const float* w4  = (const float*)d_in[14];
    const float* b4  = (const float*)d_in[15];
    const float* g4  = (const float*)d_in[16];
    const float* be4 = (const float*)d_in[17];
    const float* aw  = (const float*)d_in[18];
    float* out = (float*)d_out;

    float* ws = (float*)d_ws;
    // arena1: y1(12.85M f) -> y2(6.42M) -> y3(11.08M) -> y4(18.87M floats)
    ushort* yb  = (ushort*)ws;
    // arena2: h1(12.85M f) -> h2(6.42M) -> h3(11.08M floats)
    ushort* hb  = (ushort*)(ws + 18874368);
    ushort* wb2 = (ushort*)(ws + 31719424);
    ushort* wb3 = (ushort*)(ws + 31723520);
    ushort* wb4 = (ushort*)(ws + 31732736);
    float* sums = ws + 31769600;   // 4 layers x 8 slots x 256
    float* ab   = ws + 31777792;   // 4 layers x 256
    float* fbuf = ws + 31778816;   // 512*128
    ushort* fnh = (ushort*)(ws + 31844352);  // 512*128 f16
    float* wiv  = ws + 31877120;   // 100,000

    hipMemsetAsync(sums, 0, 4 * 2048 * sizeof(float), stream);

    // weight repacks + wnorm (independent of conv chain)
    repack<32, 16, 4><<<32, 256, 0, stream>>>(w2, wb2);
    repack<64, 32, 3><<<72, 256, 0, stream>>>(w3, wb3);
    repack<128, 64, 3><<<288, 256, 0, stream>>>(w4, wb4);
    wnorm<<<25000, 256, 0, stream>>>(aw, wiv);

    // conv1: (512,1,112,112) fp32 -> y1 (512,56,56,16) f16 NHWC
    conv1_k<<<6272, 256, 0, stream>>>(x, w1, b1, yb, sums);
    mkab<<<1, 128, 0, stream>>>(sums, g1, be1, ab, 16, 1.f / 1605632.f);
    fold<16><<<12544, 256, 0, stream>>>(yb, ab, hb);

    // conv2 -> y2 (512,28,28,32) f16 NHWC
    conv2_mfma<<<3136, 256, 0, stream>>>(hb, wb2, b2, yb, sums + 2048);
    mkab<<<1, 128, 0, stream>>>(sums + 2048, g2, be2, ab + 256, 32, 1.f / 401408.f);
    fold<32><<<6272, 256, 0, stream>>>(yb, ab + 256, hb);

    // conv3 -> y3 (512,26,26,64) f16 NHWC  (LDS-staged implicit GEMM)
    conv_lds<32, 64, 3, 28, 28, 26, 26><<<2704, 256, 0, stream>>>(hb, wb3, b3, yb, sums + 4096);
    mkab<<<1, 128, 0, stream>>>(sums + 4096, g3, be3, ab + 512, 64, 1.f / 346112.f);
    fold<64><<<10816, 256, 0, stream>>>(yb, ab + 512, hb);

    // conv4 -> y4 (512,24,24,128) f16 NHWC  (LDS-staged implicit GEMM)
    conv_lds<64, 128, 3, 26, 26, 24, 24><<<2304, 256, 0, stream>>>(hb, wb4, b4, yb, sums + 6144);
    mkab<<<1, 128, 0, stream>>>(sums + 6144, g4, be4, ab + 768, 128, 1.f / 294912.f);

    // pool (applies BN4+ReLU) + feature normalize (f16)
    pool<<<512, 256, 0, stream>>>(yb, ab + 768, fbuf);
    fnorm<<<512, 128, 0, stream>>>(fbuf, fnh);

    // cosine logits + margin + scale
    arc_gemm<<<1563, 256, 0, stream>>>(fnh, aw, wiv, gt, out);
}

// Round 2
// 643.474 us; speedup vs baseline: 1.2163x; 1.1530x over previous
//
#include <hip/hip_runtime.h>

typedef unsigned int uint;
typedef unsigned short ushort;

typedef _Float16 half8 __attribute__((ext_vector_type(8)));
typedef float f32x4 __attribute__((ext_vector_type(4)));

#define DEV __device__ __forceinline__

DEV ushort f2h(float x) {
    _Float16 h = (_Float16)x;
    ushort u;
    __builtin_memcpy(&u, &h, 2);
    return u;
}

// ---------------------------------------------------------------------------
// conv1: direct fp32 VALU (IC=1, K too small for MFMA). One thread per output
// pixel, 16 oc in registers. Output y1: NHWC f16. Fused BN stats.
// ---------------------------------------------------------------------------
__global__ __launch_bounds__(256, 2) void conv1_k(
    const float* __restrict__ x, const float* __restrict__ w,
    const float* __restrict__ bias, ushort* __restrict__ y1,
    float* __restrict__ sums)
{
    int idx = blockIdx.x * 256 + threadIdx.x;
    int ow = idx % 56;
    int oh = (idx / 56) % 56;
    int n  = idx / 3136;

    float acc[16];
#pragma unroll
    for (int o = 0; o < 16; ++o) acc[o] = bias[o];

    const float* xp = x + (size_t)n * 12544;
#pragma unroll
    for (int kh = 0; kh < 4; ++kh) {
        int ih = oh * 2 - 1 + kh;
        if ((uint)ih >= 112u) continue;
#pragma unroll
        for (int kw = 0; kw < 4; ++kw) {
            int iw = ow * 2 - 1 + kw;
            if ((uint)iw >= 112u) continue;
            float v = xp[ih * 112 + iw];
#pragma unroll
            for (int o = 0; o < 16; ++o)
                acc[o] = fmaf(v, w[o * 16 + kh * 4 + kw], acc[o]);
        }
    }

    ushort hs[16];
#pragma unroll
    for (int o = 0; o < 16; ++o) hs[o] = f2h(acc[o]);
    __builtin_memcpy(y1 + (size_t)idx * 16, hs, 32);

    // fused BN stats
    __shared__ float red[2][4][16];
    int lane = threadIdx.x & 63, wv = threadIdx.x >> 6;
#pragma unroll
    for (int o = 0; o < 16; ++o) {
        float s = acc[o], q = acc[o] * acc[o];
#pragma unroll
        for (int off = 32; off; off >>= 1) {
            s += __shfl_down(s, off);
            q += __shfl_down(q, off);
        }
        if (lane == 0) { red[0][wv][o] = s; red[1][wv][o] = q; }
    }
    __syncthreads();
    float* sl = sums + (blockIdx.x & 7) * 256;
    int t = threadIdx.x;
    if (t < 16)
        atomicAdd(&sl[t], red[0][0][t] + red[0][1][t] + red[0][2][t] + red[0][3][t]);
    else if (t >= 64 && t < 80) {
        int o = t - 64;
        atomicAdd(&sl[128 + o], red[1][0][o] + red[1][1][o] + red[1][2][o] + red[1][3][o]);
    }
}

// sums (8 slots x 256) -> (a, b) fold:  h = relu(a*y + b)
__global__ __launch_bounds__(128) void mkab(const float* __restrict__ sums,
                                            const float* __restrict__ g,
                                            const float* __restrict__ be,
                                            float* __restrict__ ab, int C, float invP)
{
    int c = threadIdx.x;
    if (c >= C) return;
    float s = 0.f, q = 0.f;
#pragma unroll
    for (int k = 0; k < 8; ++k) { s += sums[k * 256 + c]; q += sums[k * 256 + 128 + c]; }
    float mu  = s * invP;
    float var = fmaf(-mu, mu, q * invP);
    float a   = g[c] / sqrtf(var + 1e-5f);
    ab[c]     = a;
    ab[C + c] = fmaf(-mu, a, be[c]);
}

// Elementwise fold: h = f16(relu(a*y + b)), NHWC, C = power of 2.
template <int C>
__global__ __launch_bounds__(256) void fold(const ushort* __restrict__ y,
                                            const float* __restrict__ ab,
                                            ushort* __restrict__ h)
{
    __shared__ float sa[C], sb[C];
    if (threadIdx.x < C) { sa[threadIdx.x] = ab[threadIdx.x]; sb[threadIdx.x] = ab[C + threadIdx.x]; }
    __syncthreads();
    int idx = blockIdx.x * 256 + threadIdx.x;
    half8 v;
    __builtin_memcpy(&v, y + (size_t)idx * 8, 16);
    int c0 = (idx * 8) & (C - 1);
    half8 o;
#pragma unroll
    for (int e = 0; e < 8; ++e) {
        float f = (float)v[e];
        o[e] = (_Float16)fmaxf(fmaf(sa[c0 + e], f, sb[c0 + e]), 0.f);
    }
    __builtin_memcpy(h + (size_t)idx * 8, &o, 16);
}

// Repack conv weights OIHW fp32 -> [oc][kh][kw][ic] f16.  (conv2 layout)
template <int OC, int IC, int K>
__global__ __launch_bounds__(256) void repack(const float* __restrict__ w,
                                              ushort* __restrict__ wb)
{
    int i = blockIdx.x * 256 + threadIdx.x;
    int ic = i % IC;
    int r  = i / IC;
    int kw = r % K;  r /= K;
    int kh = r % K;
    int oc = r / K;
    wb[i] = f2h(w[((oc * IC + ic) * K + kh) * K + kw]);
}

// Repack conv weights OIHW fp32 -> chunk-major [q][oc][32] f16, where
// q = (kh*K + kw)*(IC/32) + ic/32. A wave's per-(chunk,t) B fragment is then
// one contiguous 1KB burst.
template <int OC, int IC, int K>
__global__ __launch_bounds__(256) void repack_cm(const float* __restrict__ w,
                                                 ushort* __restrict__ wb)
{
    constexpr int NC = IC / 32;
    int i = blockIdx.x * 256 + threadIdx.x;
    int e  = i & 31;
    int oc = (i >> 5) % OC;
    int q  = i / (32 * OC);
    int c  = q % NC;
    int r  = q / NC;
    int kw = r % K, kh = r / K;
    int ic = c * 32 + e;
    wb[i] = f2h(w[((oc * IC + ic) * K + kh) * K + kw]);
}

// ---------------------------------------------------------------------------
// conv2: implicit GEMM, K=4 S=2 P=1, IC=16 OC=32, in (512,56,56,16) f16 NHWC.
// ---------------------------------------------------------------------------
__global__ __launch_bounds__(256, 2) void conv2_mfma(
    const ushort* __restrict__ hin, const ushort* __restrict__ wb,
    const float* __restrict__ bias, ushort* __restrict__ y,
    float* __restrict__ sums)
{
    const int lane = threadIdx.x & 63, wv = threadIdx.x >> 6;
    const int col = lane & 15, quad = lane >> 4;
    const int kwoff = quad >> 1;
    const int icoff = (quad & 1) * 8;
    const int mbase = blockIdx.x * 128 + wv * 32;

    int nb[2], ihb[2], iwb[2];
#pragma unroll
    for (int s = 0; s < 2; ++s) {
        int m = mbase + s * 16 + col;
        int n = m / 784, rem = m % 784;
        int oh = rem / 28, ow = rem % 28;
        nb[s]  = n * 50176 + icoff;   // n*IH*IW*IC + ic offset (halfs)
        ihb[s] = oh * 2 - 1;
        iwb[s] = ow * 2 - 1 + kwoff;
    }

    float bv[2];
#pragma unroll
    for (int t = 0; t < 2; ++t) bv[t] = bias[t * 16 + col];

    f32x4 acc[2][2];
#pragma unroll
    for (int s = 0; s < 2; ++s)
#pragma unroll
        for (int t = 0; t < 2; ++t) acc[s][t] = (f32x4){0.f, 0.f, 0.f, 0.f};

    const int wrow = col * 256 + icoff;  // oc*K*K*IC + icoff

#pragma unroll
    for (int kh = 0; kh < 4; ++kh) {
#pragma unroll
        for (int kwp = 0; kwp < 2; ++kwp) {
            half8 af[2];
#pragma unroll
            for (int s = 0; s < 2; ++s) {
                int ih = ihb[s] + kh;
                int iw = iwb[s] + kwp * 2;
                uint r0 = 0, r1 = 0, r2 = 0, r3 = 0;
                if ((uint)ih < 56u && (uint)iw < 56u) {
                    uint raw[4];
                    __builtin_memcpy(raw, hin + nb[s] + ih * 896 + iw * 16, 16);
                    r0 = raw[0]; r1 = raw[1]; r2 = raw[2]; r3 = raw[3];
                }
                uint raw2[4] = {r0, r1, r2, r3};
                __builtin_memcpy(&af[s], raw2, 16);
            }
            const int boff = (kh * 4 + kwp * 2 + kwoff) * 16;
#pragma unroll
            for (int t = 0; t < 2; ++t) {
                half8 bf;
                __builtin_memcpy(&bf, wb + wrow + t * 4096 + boff, 16);
#pragma unroll
                for (int s = 0; s < 2; ++s)
                    acc[s][t] = __builtin_amdgcn_mfma_f32_16x16x32_f16(af[s], bf, acc[s][t], 0, 0, 0);
            }
        }
    }

    // epilogue: bias, f16 store (NHWC), fused stats
    float ss[2] = {0.f, 0.f}, qq[2] = {0.f, 0.f};
#pragma unroll
    for (int s = 0; s < 2; ++s) {
        int m0 = mbase + s * 16 + quad * 4;
#pragma unroll
        for (int t = 0; t < 2; ++t) {
#pragma unroll
            for (int r = 0; r < 4; ++r) {
                float yv = acc[s][t][r] + bv[t];
                ss[t] += yv;
                qq[t] = fmaf(yv, yv, qq[t]);
                y[(size_t)(m0 + r) * 32 + t * 16 + col] = f2h(yv);
            }
        }
    }
    __shared__ float redS[4][32], redQ[4][32];
#pragma unroll
    for (int t = 0; t < 2; ++t) {
        float s = ss[t], q = qq[t];
        s += __shfl_xor(s, 16); s += __shfl_xor(s, 32);
        q += __shfl_xor(q, 16); q += __shfl_xor(q, 32);
        if (quad == 0) { redS[wv][t * 16 + col] = s; redQ[wv][t * 16 + col] = q; }
    }
    __syncthreads();
    int t0 = threadIdx.x;
    float* sl = sums + (blockIdx.x & 7) * 256;
    if (t0 < 32)
        atomicAdd(&sl[t0], redS[0][t0] + redS[1][t0] + redS[2][t0] + redS[3][t0]);
    else if (t0 >= 128 && t0 < 160) {
        int c = t0 - 128;
        atomicAdd(&sl[128 + c], redQ[0][c] + redQ[1][c] + redQ[2][c] + redQ[3][c]);
    }
}

// ---------------------------------------------------------------------------
// conv3/conv4 (K=3, S=1, P=0): implicit GEMM. Block = 256 m-rows (4 waves x
// 4 sub-tiles of 16). A slab (<=13 input rows, contiguous linear row range)
// staged once into LDS via global_load_lds (linear dest, XOR-swizzled source;
// reads apply the same involution). B is chunk-major ([q][oc][32]) so each
// per-(chunk,t) fragment load is a contiguous 1KB wave burst, register
// double-buffered one chunk ahead; all 4 waves read the same lines -> L1 hits.
// ---------------------------------------------------------------------------
template <int IC, int OC, int K, int IH, int IW, int OH, int OW>
__global__ __launch_bounds__(256, 2) void conv_lds(
    const ushort* __restrict__ hin, const ushort* __restrict__ wb,
    const float* __restrict__ bias, ushort* __restrict__ y,
    float* __restrict__ sums)
{
    constexpr int NT  = OC / 16, NC = IC / 32;
    constexpr int NCH = K * K * NC;
    constexpr int ROWB = IW * IC * 2;                         // bytes / input row
    constexpr int MAXR = 255 / OW + K;                        // max rows spanned
    constexpr int SLAB = ((MAXR * ROWB + 4095) / 4096) * 4096;
    __shared__ ushort slab[SLAB / 2];
    __shared__ float redS[4][OC], redQ[4][OC];

    const int lane = threadIdx.x & 63, wv = threadIdx.x >> 6;
    const int col = lane & 15, quad = lane >> 4;
    const int mbase = blockIdx.x * 256 + wv * 64;

    // block input row range (linear rows, contiguous even across images)
    const int m0  = blockIdx.x * 256;
    const int rl0 = (m0 / (OH * OW)) * IH + (m0 % (OH * OW)) / OW;
    const int mL  = m0 + 255;
    const int rl1 = (mL / (OH * OW)) * IH + (mL % (OH * OW)) / OW + (K - 1);
    const int stage_bytes = (rl1 - rl0 + 1) * ROWB;

    // stage A slab: linear LDS dest, pre-swizzled global source
    {
        const char* src = (const char*)(hin + (size_t)rl0 * (IW * IC));
        char* dst = (char*)slab;
        int d = threadIdx.x * 16;
        int rounds = (stage_bytes + 4095) >> 12;
        for (int r = 0; r < rounds; ++r) {
            int sw = d ^ (((d >> 7) & 7) << 4);
            __builtin_amdgcn_global_load_lds(
                (const __attribute__((address_space(1))) void*)(src + sw),
                (__attribute__((address_space(3))) void*)(dst + d), 16, 0, 0);
            d += 4096;
        }
    }

    // per-lane A base offset in halfs (pre-swizzle, relative to slab)
    int aloc[4];
#pragma unroll
    for (int s = 0; s < 4; ++s) {
        int m = mbase + s * 16 + col;
        int n = m / (OH * OW), rem = m % (OH * OW);
        int oh = rem / OW, ow = rem % OW;
        aloc[s] = ((n * IH + oh - rl0) * IW + ow) * IC + quad * 8;
    }
    const int bcol = col * 32 + quad * 8;   // lane offset within [oc][32] chunk

    f32x4 acc[4][NT];
#pragma unroll
    for (int s = 0; s < 4; ++s)
#pragma unroll
        for (int t = 0; t < NT; ++t) acc[s][t] = (f32x4){0.f, 0.f, 0.f, 0.f};

    // prologue B load (chunk 0) — independent of LDS, overlaps the stage drain
    half8 bbuf[2][NT];
#pragma unroll
    for (int t = 0; t < NT; ++t)
        __builtin_memcpy(&bbuf[0][t], wb + t * 512 + bcol, 16);

    __syncthreads();   // drains vmcnt(0): slab (and chunk-0 B) complete

#pragma unroll
    for (int q = 0; q < NCH; ++q) {
        // prefetch next chunk's B into the other register buffer
        if (q + 1 < NCH) {
            const ushort* bp = wb + (q + 1) * (OC * 32) + bcol;
#pragma unroll
            for (int t = 0; t < NT; ++t)
                __builtin_memcpy(&bbuf[(q + 1) & 1][t], bp + t * 512, 16);
        }
        const int kh = q / (K * NC), kw = (q / NC) % K, c = q % NC;
        const int aoff = (kh * IW + kw) * IC + c * 32;
#pragma unroll
        for (int s = 0; s < 4; ++s) {
            half8 af;
            int b = 2 * (aloc[s] + aoff);
            b ^= ((b >> 7) & 7) << 4;            // same involution as stage
            __builtin_memcpy(&af, (const char*)slab + b, 16);
#pragma unroll
            for (int t = 0; t < NT; ++t)
                acc[s][t] = __builtin_amdgcn_mfma_f32_16x16x32_f16(af, bbuf[q & 1][t], acc[s][t], 0, 0, 0);
        }
    }

    // epilogue: bias, f16 store (NHWC), fused stats
    float bv[NT];
#pragma unroll
    for (int t = 0; t < NT; ++t) bv[t] = bias[t * 16 + col];

    float ss[NT], qq[NT];
#pragma unroll
    for (int t = 0; t < NT; ++t) { ss[t] = 0.f; qq[t] = 0.f; }
#pragma unroll
    for (int s = 0; s < 4; ++s) {
        int me = mbase + s * 16 + quad * 4;
#pragma unroll
        for (int t = 0; t < NT; ++t) {
#pragma unroll
            for (int r = 0; r < 4; ++r) {
                float yv = acc[s][t][r] + bv[t];
                ss[t] += yv;
                qq[t] = fmaf(yv, yv, qq[t]);
                y[(size_t)(me + r) * OC + t * 16 + col] = f2h(yv);
            }
        }
    }
#pragma unroll
    for (int t = 0; t < NT; ++t) {
        float s = ss[t], q = qq[t];
        s += __shfl_xor(s, 16); s += __shfl_xor(s, 32);
        q += __shfl_xor(q, 16); q += __shfl_xor(q, 32);
        if (quad == 0) { redS[wv][t * 16 + col] = s; redQ[wv][t * 16 + col] = q; }
    }
    __syncthreads();
    int t0 = threadIdx.x;
    float* sl = sums + (blockIdx.x & 7) * 256;
    if (t0 < OC)
        atomicAdd(&sl[t0], redS[0][t0] + redS[1][t0] + redS[2][t0] + redS[3][t0]);
    else if (t0 >= 128 && t0 < 128 + OC) {
        int c = t0 - 128;
        atomicAdd(&sl[128 + c], redQ[0][c] + redQ[1][c] + redQ[2][c] + redQ[3][c]);
    }
}

// Global average pool over y4 (512,24,24,128) f16 NHWC, BN4+ReLU applied.
__global__ __launch_bounds__(256) void pool(const ushort* __restrict__ y4,
                                            const float* __restrict__ ab,
                                            float* __restrict__ f)
{
    int n = blockIdx.x;
    int c = threadIdx.x & 127, ph = threadIdx.x >> 7;
    const ushort* p = y4 + (size_t)n * 73728 + c;
    float a = ab[c], b = ab[128 + c];
    float s = 0.f;
    for (int i = ph * 288; i < ph * 288 + 288; ++i) {
        _Float16 hv;
        __builtin_memcpy(&hv, p + i * 128, 2);
        s += fmaxf(fmaf(a, (float)hv, b), 0.f);
    }
    __shared__ float l[128];
    if (ph == 1) l[c] = s;
    __syncthreads();
    if (ph == 0) f[n * 128 + c] = (s + l[c]) * (1.f / 576.f);
}

// L2-normalize feature rows, emit f16.
__global__ __launch_bounds__(128) void fnorm(const float* __restrict__ f,
                                             ushort* __restrict__ fnh)
{
    int n = blockIdx.x, t = threadIdx.x;
    float v = f[n * 128 + t];
    float q = v * v;
    for (int off = 32; off; off >>= 1) q += __shfl_down(q, off);
    __shared__ float l[2];
    if ((t & 63) == 0) l[t >> 6] = q;
    __syncthreads();
    float inv = 1.f / fmaxf(sqrtf(l[0] + l[1]), 1e-12f);
    fnh[n * 128 + t] = f2h(v * inv);
}

// arc_w row inverse norms. One wave per row.
__global__ __launch_bounds__(256) void wnorm(const float* __restrict__ w,
                                             float* __restrict__ winv)
{
    int wv = threadIdx.x >> 6, lane = threadIdx.x & 63;
    int j = blockIdx.x * 4 + wv;
    const float* p = w + (size_t)j * 128;
    float v0 = p[lane], v1 = p[lane + 64];
    float q = fmaf(v0, v0, v1 * v1);
    for (int off = 32; off; off >>= 1) q += __shfl_down(q, off);
    if (lane == 0) winv[j] = 1.f / fmaxf(sqrtf(q), 1e-12f);
}

// ---------------------------------------------------------------------------
// Final GEMM: out[i][j] = 64 * (fn[i] . wn[j]), margin fix at j == gt[i].
// M=512, N=100000, K=128. f16 MFMA 16x16x32, fp32 accumulate.
// ---------------------------------------------------------------------------
__global__ __launch_bounds__(256) void arc_gemm(const ushort* __restrict__ fnh,
                                                const float* __restrict__ aw,
                                                const float* __restrict__ winv,
                                                const int* __restrict__ gt,
                                                float* __restrict__ out)
{
    const int lane = threadIdx.x & 63, wv = threadIdx.x >> 6;
    const int col = lane & 15, quad = lane >> 4;
    const int j = blockIdx.x * 64 + wv * 16 + col;
    const bool jvalid = (j < 100000);
    const int jc = jvalid ? j : 99999;

    const float wi = winv[jc];
    const float* wp = aw + (size_t)jc * 128 + quad * 8;
    half8 bfr[4];
#pragma unroll
    for (int s = 0; s < 4; ++s) {
        half8 t;
#pragma unroll
        for (int e = 0; e < 8; ++e) t[e] = (_Float16)(wp[s * 32 + e] * wi);
        bfr[s] = t;
    }

    const float cm = 0.87758256189037272f;  // cos(0.5)
    const float sm = 0.47942553860420301f;  // sin(0.5)

    for (int mt = 0; mt < 32; ++mt) {
        const ushort* ap = fnh + (size_t)(mt * 16 + col) * 128 + quad * 8;
        f32x4 acc = {0.f, 0.f, 0.f, 0.f};
#pragma unroll
        for (int s = 0; s < 4; ++s) {
            half8 af;
            __builtin_memcpy(&af, ap + s * 32, 16);
            acc = __builtin_amdgcn_mfma_f32_16x16x32_f16(af, bfr[s], acc, 0, 0, 0);
        }
#pragma unroll
        for (int r = 0; r < 4; ++r) {
            int row = mt * 16 + quad * 4 + r;
            float v = acc[r];
            float o = 64.f * v;
            if (gt[row] == j) {
                float t = fmaxf(1.f - v * v, 0.f);
                o = 64.f * fmaf(v, cm, -sqrtf(t) * sm);
            }
            if (jvalid) out[(size_t)row * 100000 + j] = o;
        }
    }
}

// ---------------------------------------------------------------------------
extern "C" void kernel_launch(void* const* d_in, const int* in_sizes, int n_in,
                              void* d_out, int out_size, void* d_ws, size_t ws_size,
                              hipStream_t stream)
{
    const float* x   = (const float*)d_in[0];
    const int*   gt  = (const int*)d_in[1];
    const float* w1  = (const float*)d_in[2];
    const float* b1  = (const float*)d_in[3];
    const float* g1  = (const float*)d_in[4];
    const float* be1 = (const float*)d_in[5];
    const float* w2  = (const float*)d_in[6];
    const float* b2  = (const float*)d_in[7];
    const float* g2  = (const float*)d_in[8];
    const float* be2 = (const float*)d_in[9];
    const float* w3  = (const float*)d_in[10];
    const float* b3  = (const float*)d_in[11];
    const float* g3  = (const float*)d_in[12];
    const float* be3 = (const float*)d_in[13];
    const float* w4  = (const float*)d_in[14];
    const float* b4  = (const float*)d_in[15];
    const float* g4  = (const float*)d_in[16];
    const float* be4 = (const float*)d_in[17];
    const float* aw  = (const float*)d_in[18];
    float* out = (float*)d_out;

    float* ws = (float*)d_ws;
    // arena1: y1(12.85M f) -> y2(6.42M) -> y3(11.08M) -> y4(18.87M floats)
    ushort* yb  = (ushort*)ws;
    // arena2: h1(12.85M f) -> h2(6.42M) -> h3(11.08M floats)
    ushort* hb  = (ushort*)(ws + 18874368);
    ushort* wb2 = (ushort*)(ws + 31719424);
    ushort* wb3 = (ushort*)(ws + 31723520);
    ushort* wb4 = (ushort*)(ws + 31732736);
    float* sums = ws + 31769600;   // 4 layers x 8 slots x 256
    float* ab   = ws + 31777792;   // 4 layers x 256
    float* fbuf = ws + 31778816;   // 512*128
    ushort* fnh = (ushort*)(ws + 31844352);  // 512*128 f16
    float* wiv  = ws + 31877120;   // 100,000

    hipMemsetAsync(sums, 0, 4 * 2048 * sizeof(float), stream);

    // weight repacks + wnorm (independent of conv chain)
    repack<32, 16, 4><<<32, 256, 0, stream>>>(w2, wb2);
    repack_cm<64, 32, 3><<<72, 256, 0, stream>>>(w3, wb3);
    repack_cm<128, 64, 3><<<288, 256, 0, stream>>>(w4, wb4);
    wnorm<<<25000, 256, 0, stream>>>(aw, wiv);

    // conv1: (512,1,112,112) fp32 -> y1 (512,56,56,16) f16 NHWC
    conv1_k<<<6272, 256, 0, stream>>>(x, w1, b1, yb, sums);
    mkab<<<1, 128, 0, stream>>>(sums, g1, be1, ab, 16, 1.f / 1605632.f);
    fold<16><<<12544, 256, 0, stream>>>(yb, ab, hb);

    // conv2 -> y2 (512,28,28,32) f16 NHWC
    conv2_mfma<<<3136, 256, 0, stream>>>(hb, wb2, b2, yb, sums + 2048);
    mkab<<<1, 128, 0, stream>>>(sums + 2048, g2, be2, ab + 256, 32, 1.f / 401408.f);
    fold<32><<<6272, 256, 0, stream>>>(yb, ab + 256, hb);

    // conv3 -> y3 (512,26,26,64) f16 NHWC  (LDS-staged, chunk-major B)
    conv_lds<32, 64, 3, 28, 28, 26, 26><<<1352, 256, 0, stream>>>(hb, wb3, b3, yb, sums + 4096);
    mkab<<<1, 128, 0, stream>>>(sums + 4096, g3, be3, ab + 512, 64, 1.f / 346112.f);
    fold<64><<<10816, 256, 0, stream>>>(yb, ab + 512, hb);

    // conv4 -> y4 (512,24,24,128) f16 NHWC  (LDS-staged, chunk-major B)
    conv_lds<64, 128, 3, 26, 26, 24, 24><<<1152, 256, 0, stream>>>(hb, wb4, b4, yb, sums + 6144);
    mkab<<<1, 128, 0, stream>>>(sums + 6144, g4, be4, ab + 768, 128, 1.f / 294912.f);

    // pool (applies BN4+ReLU) + feature normalize (f16)
    pool<<<512, 256, 0, stream>>>(yb, ab + 768, fbuf);
    fnorm<<<512, 128, 0, stream>>>(fbuf, fnh);

    // cosine logits + margin + scale
    arc_gemm<<<1563, 256, 0, stream>>>(fnh, aw, wiv, gt, out);
}

// Round 3
// 634.480 us; speedup vs baseline: 1.2335x; 1.0142x over previous
//
#include <hip/hip_runtime.h>

typedef unsigned int uint;
typedef unsigned short ushort;

typedef _Float16 half8 __attribute__((ext_vector_type(8)));
typedef float f32x4 __attribute__((ext_vector_type(4)));

#define DEV __device__ __forceinline__

DEV ushort f2h(float x) {
    _Float16 h = (_Float16)x;
    ushort u;
    __builtin_memcpy(&u, &h, 2);
    return u;
}

// ---------------------------------------------------------------------------
// conv1: direct fp32 VALU (IC=1, K too small for MFMA). One thread per output
// pixel, 16 oc in registers. Output y1: NHWC f16. Fused BN stats.
// ---------------------------------------------------------------------------
__global__ __launch_bounds__(256, 2) void conv1_k(
    const float* __restrict__ x, const float* __restrict__ w,
    const float* __restrict__ bias, ushort* __restrict__ y1,
    float* __restrict__ sums)
{
    int idx = blockIdx.x * 256 + threadIdx.x;
    int ow = idx % 56;
    int oh = (idx / 56) % 56;
    int n  = idx / 3136;

    float acc[16];
#pragma unroll
    for (int o = 0; o < 16; ++o) acc[o] = bias[o];

    const float* xp = x + (size_t)n * 12544;
#pragma unroll
    for (int kh = 0; kh < 4; ++kh) {
        int ih = oh * 2 - 1 + kh;
        if ((uint)ih >= 112u) continue;
#pragma unroll
        for (int kw = 0; kw < 4; ++kw) {
            int iw = ow * 2 - 1 + kw;
            if ((uint)iw >= 112u) continue;
            float v = xp[ih * 112 + iw];
#pragma unroll
            for (int o = 0; o < 16; ++o)
                acc[o] = fmaf(v, w[o * 16 + kh * 4 + kw], acc[o]);
        }
    }

    ushort hs[16];
#pragma unroll
    for (int o = 0; o < 16; ++o) hs[o] = f2h(acc[o]);
    __builtin_memcpy(y1 + (size_t)idx * 16, hs, 32);

    // fused BN stats
    __shared__ float red[2][4][16];
    int lane = threadIdx.x & 63, wv = threadIdx.x >> 6;
#pragma unroll
    for (int o = 0; o < 16; ++o) {
        float s = acc[o], q = acc[o] * acc[o];
#pragma unroll
        for (int off = 32; off; off >>= 1) {
            s += __shfl_down(s, off);
            q += __shfl_down(q, off);
        }
        if (lane == 0) { red[0][wv][o] = s; red[1][wv][o] = q; }
    }
    __syncthreads();
    float* sl = sums + (blockIdx.x & 7) * 256;
    int t = threadIdx.x;
    if (t < 16)
        atomicAdd(&sl[t], red[0][0][t] + red[0][1][t] + red[0][2][t] + red[0][3][t]);
    else if (t >= 64 && t < 80) {
        int o = t - 64;
        atomicAdd(&sl[128 + o], red[1][0][o] + red[1][1][o] + red[1][2][o] + red[1][3][o]);
    }
}

// sums (8 slots x 256) -> (a, b) fold:  h = relu(a*y + b)
__global__ __launch_bounds__(128) void mkab(const float* __restrict__ sums,
                                            const float* __restrict__ g,
                                            const float* __restrict__ be,
                                            float* __restrict__ ab, int C, float invP)
{
    int c = threadIdx.x;
    if (c >= C) return;
    float s = 0.f, q = 0.f;
#pragma unroll
    for (int k = 0; k < 8; ++k) { s += sums[k * 256 + c]; q += sums[k * 256 + 128 + c]; }
    float mu  = s * invP;
    float var = fmaf(-mu, mu, q * invP);
    float a   = g[c] / sqrtf(var + 1e-5f);
    ab[c]     = a;
    ab[C + c] = fmaf(-mu, a, be[c]);
}

// Elementwise fold: h = f16(relu(a*y + b)), NHWC, C = power of 2.
template <int C>
__global__ __launch_bounds__(256) void fold(const ushort* __restrict__ y,
                                            const float* __restrict__ ab,
                                            ushort* __restrict__ h)
{
    __shared__ float sa[C], sb[C];
    if (threadIdx.x < C) { sa[threadIdx.x] = ab[threadIdx.x]; sb[threadIdx.x] = ab[C + threadIdx.x]; }
    __syncthreads();
    int idx = blockIdx.x * 256 + threadIdx.x;
    half8 v;
    __builtin_memcpy(&v, y + (size_t)idx * 8, 16);
    int c0 = (idx * 8) & (C - 1);
    half8 o;
#pragma unroll
    for (int e = 0; e < 8; ++e) {
        float f = (float)v[e];
        o[e] = (_Float16)fmaxf(fmaf(sa[c0 + e], f, sb[c0 + e]), 0.f);
    }
    __builtin_memcpy(h + (size_t)idx * 8, &o, 16);
}

// Repack conv weights OIHW fp32 -> [oc][kh][kw][ic] f16.  (conv2 layout)
template <int OC, int IC, int K>
__global__ __launch_bounds__(256) void repack(const float* __restrict__ w,
                                              ushort* __restrict__ wb)
{
    int i = blockIdx.x * 256 + threadIdx.x;
    int ic = i % IC;
    int r  = i / IC;
    int kw = r % K;  r /= K;
    int kh = r % K;
    int oc = r / K;
    wb[i] = f2h(w[((oc * IC + ic) * K + kh) * K + kw]);
}

// Repack conv weights OIHW fp32 -> chunk-major [q][oc][32] f16, where
// q = (kh*K + kw)*(IC/32) + ic/32. A wave's per-(chunk,t) B fragment is then
// one contiguous 1KB burst.
template <int OC, int IC, int K>
__global__ __launch_bounds__(256) void repack_cm(const float* __restrict__ w,
                                                 ushort* __restrict__ wb)
{
    constexpr int NC = IC / 32;
    int i = blockIdx.x * 256 + threadIdx.x;
    int e  = i & 31;
    int oc = (i >> 5) % OC;
    int q  = i / (32 * OC);
    int c  = q % NC;
    int r  = q / NC;
    int kw = r % K, kh = r / K;
    int ic = c * 32 + e;
    wb[i] = f2h(w[((oc * IC + ic) * K + kh) * K + kw]);
}

// ---------------------------------------------------------------------------
// conv2: implicit GEMM, K=4 S=2 P=1, IC=16 OC=32, in (512,56,56,16) f16 NHWC.
// ---------------------------------------------------------------------------
__global__ __launch_bounds__(256, 2) void conv2_mfma(
    const ushort* __restrict__ hin, const ushort* __restrict__ wb,
    const float* __restrict__ bias, ushort* __restrict__ y,
    float* __restrict__ sums)
{
    const int lane = threadIdx.x & 63, wv = threadIdx.x >> 6;
    const int col = lane & 15, quad = lane >> 4;
    const int kwoff = quad >> 1;
    const int icoff = (quad & 1) * 8;
    const int mbase = blockIdx.x * 128 + wv * 32;

    int nb[2], ihb[2], iwb[2];
#pragma unroll
    for (int s = 0; s < 2; ++s) {
        int m = mbase + s * 16 + col;
        int n = m / 784, rem = m % 784;
        int oh = rem / 28, ow = rem % 28;
        nb[s]  = n * 50176 + icoff;   // n*IH*IW*IC + ic offset (halfs)
        ihb[s] = oh * 2 - 1;
        iwb[s] = ow * 2 - 1 + kwoff;
    }

    float bv[2];
#pragma unroll
    for (int t = 0; t < 2; ++t) bv[t] = bias[t * 16 + col];

    f32x4 acc[2][2];
#pragma unroll
    for (int s = 0; s < 2; ++s)
#pragma unroll
        for (int t = 0; t < 2; ++t) acc[s][t] = (f32x4){0.f, 0.f, 0.f, 0.f};

    const int wrow = col * 256 + icoff;  // oc*K*K*IC + icoff

#pragma unroll
    for (int kh = 0; kh < 4; ++kh) {
#pragma unroll
        for (int kwp = 0; kwp < 2; ++kwp) {
            half8 af[2];
#pragma unroll
            for (int s = 0; s < 2; ++s) {
                int ih = ihb[s] + kh;
                int iw = iwb[s] + kwp * 2;
                uint r0 = 0, r1 = 0, r2 = 0, r3 = 0;
                if ((uint)ih < 56u && (uint)iw < 56u) {
                    uint raw[4];
                    __builtin_memcpy(raw, hin + nb[s] + ih * 896 + iw * 16, 16);
                    r0 = raw[0]; r1 = raw[1]; r2 = raw[2]; r3 = raw[3];
                }
                uint raw2[4] = {r0, r1, r2, r3};
                __builtin_memcpy(&af[s], raw2, 16);
            }
            const int boff = (kh * 4 + kwp * 2 + kwoff) * 16;
#pragma unroll
            for (int t = 0; t < 2; ++t) {
                half8 bf;
                __builtin_memcpy(&bf, wb + wrow + t * 4096 + boff, 16);
#pragma unroll
                for (int s = 0; s < 2; ++s)
                    acc[s][t] = __builtin_amdgcn_mfma_f32_16x16x32_f16(af[s], bf, acc[s][t], 0, 0, 0);
            }
        }
    }

    // epilogue: bias, f16 store (NHWC), fused stats
    float ss[2] = {0.f, 0.f}, qq[2] = {0.f, 0.f};
#pragma unroll
    for (int s = 0; s < 2; ++s) {
        int m0 = mbase + s * 16 + quad * 4;
#pragma unroll
        for (int t = 0; t < 2; ++t) {
#pragma unroll
            for (int r = 0; r < 4; ++r) {
                float yv = acc[s][t][r] + bv[t];
                ss[t] += yv;
                qq[t] = fmaf(yv, yv, qq[t]);
                y[(size_t)(m0 + r) * 32 + t * 16 + col] = f2h(yv);
            }
        }
    }
    __shared__ float redS[4][32], redQ[4][32];
#pragma unroll
    for (int t = 0; t < 2; ++t) {
        float s = ss[t], q = qq[t];
        s += __shfl_xor(s, 16); s += __shfl_xor(s, 32);
        q += __shfl_xor(q, 16); q += __shfl_xor(q, 32);
        if (quad == 0) { redS[wv][t * 16 + col] = s; redQ[wv][t * 16 + col] = q; }
    }
    __syncthreads();
    int t0 = threadIdx.x;
    float* sl = sums + (blockIdx.x & 7) * 256;
    if (t0 < 32)
        atomicAdd(&sl[t0], redS[0][t0] + redS[1][t0] + redS[2][t0] + redS[3][t0]);
    else if (t0 >= 128 && t0 < 160) {
        int c = t0 - 128;
        atomicAdd(&sl[128 + c], redQ[0][c] + redQ[1][c] + redQ[2][c] + redQ[3][c]);
    }
}

// ---------------------------------------------------------------------------
// conv3/conv4 (K=3, S=1, P=0): implicit GEMM. Block = 256 m-rows (4 waves x
// 4 sub-tiles of 16). A slab (<=13 input rows, contiguous linear row range)
// staged once into LDS via global_load_lds (linear dest, XOR-swizzled source;
// reads apply the same involution). B is chunk-major ([q][oc][32]) so each
// per-(chunk,t) fragment load is a contiguous 1KB wave burst, register
// double-buffered one chunk ahead; all 4 waves read the same lines -> L1 hits.
// ---------------------------------------------------------------------------
template <int IC, int OC, int K, int IH, int IW, int OH, int OW>
__global__ __launch_bounds__(256, 2) void conv_lds(
    const ushort* __restrict__ hin, const ushort* __restrict__ wb,
    const float* __restrict__ bias, ushort* __restrict__ y,
    float* __restrict__ sums)
{
    constexpr int NT  = OC / 16, NC = IC / 32;
    constexpr int NCH = K * K * NC;
    constexpr int ROWB = IW * IC * 2;                         // bytes / input row
    constexpr int MAXR = 255 / OW + K;                        // max rows spanned
    constexpr int SLAB = ((MAXR * ROWB + 4095) / 4096) * 4096;
    __shared__ ushort slab[SLAB / 2];
    __shared__ float redS[4][OC], redQ[4][OC];

    const int lane = threadIdx.x & 63, wv = threadIdx.x >> 6;
    const int col = lane & 15, quad = lane >> 4;
    const int mbase = blockIdx.x * 256 + wv * 64;

    // block input row range (linear rows, contiguous even across images)
    const int m0  = blockIdx.x * 256;
    const int rl0 = (m0 / (OH * OW)) * IH + (m0 % (OH * OW)) / OW;
    const int mL  = m0 + 255;
    const int rl1 = (mL / (OH * OW)) * IH + (mL % (OH * OW)) / OW + (K - 1);
    const int stage_bytes = (rl1 - rl0 + 1) * ROWB;

    // stage A slab: linear LDS dest, pre-swizzled global source
    {
        const char* src = (const char*)(hin + (size_t)rl0 * (IW * IC));
        char* dst = (char*)slab;
        int d = threadIdx.x * 16;
        int rounds = (stage_bytes + 4095) >> 12;
        for (int r = 0; r < rounds; ++r) {
            int sw = d ^ (((d >> 7) & 7) << 4);
            __builtin_amdgcn_global_load_lds(
                (const __attribute__((address_space(1))) void*)(src + sw),
                (__attribute__((address_space(3))) void*)(dst + d), 16, 0, 0);
            d += 4096;
        }
    }

    // per-lane A base offset in halfs (pre-swizzle, relative to slab)
    int aloc[4];
#pragma unroll
    for (int s = 0; s < 4; ++s) {
        int m = mbase + s * 16 + col;
        int n = m / (OH * OW), rem = m % (OH * OW);
        int oh = rem / OW, ow = rem % OW;
        aloc[s] = ((n * IH + oh - rl0) * IW + ow) * IC + quad * 8;
    }
    const int bcol = col * 32 + quad * 8;   // lane offset within [oc][32] chunk

    f32x4 acc[4][NT];
#pragma unroll
    for (int s = 0; s < 4; ++s)
#pragma unroll
        for (int t = 0; t < NT; ++t) acc[s][t] = (f32x4){0.f, 0.f, 0.f, 0.f};

    // prologue B load (chunk 0) — independent of LDS, overlaps the stage drain
    half8 bbuf[2][NT];
#pragma unroll
    for (int t = 0; t < NT; ++t)
        __builtin_memcpy(&bbuf[0][t], wb + t * 512 + bcol, 16);

    __syncthreads();   // drains vmcnt(0): slab (and chunk-0 B) complete

#pragma unroll
    for (int q = 0; q < NCH; ++q) {
        // prefetch next chunk's B into the other register buffer
        if (q + 1 < NCH) {
            const ushort* bp = wb + (q + 1) * (OC * 32) + bcol;
#pragma unroll
            for (int t = 0; t < NT; ++t)
                __builtin_memcpy(&bbuf[(q + 1) & 1][t], bp + t * 512, 16);
        }
        const int kh = q / (K * NC), kw = (q / NC) % K, c = q % NC;
        const int aoff = (kh * IW + kw) * IC + c * 32;
#pragma unroll
        for (int s = 0; s < 4; ++s) {
            half8 af;
            int b = 2 * (aloc[s] + aoff);
            b ^= ((b >> 7) & 7) << 4;            // same involution as stage
            __builtin_memcpy(&af, (const char*)slab + b, 16);
#pragma unroll
            for (int t = 0; t < NT; ++t)
                acc[s][t] = __builtin_amdgcn_mfma_f32_16x16x32_f16(af, bbuf[q & 1][t], acc[s][t], 0, 0, 0);
        }
    }

    // epilogue: bias, f16 store (NHWC), fused stats
    float bv[NT];
#pragma unroll
    for (int t = 0; t < NT; ++t) bv[t] = bias[t * 16 + col];

    float ss[NT], qq[NT];
#pragma unroll
    for (int t = 0; t < NT; ++t) { ss[t] = 0.f; qq[t] = 0.f; }
#pragma unroll
    for (int s = 0; s < 4; ++s) {
        int me = mbase + s * 16 + quad * 4;
#pragma unroll
        for (int t = 0; t < NT; ++t) {
#pragma unroll
            for (int r = 0; r < 4; ++r) {
                float yv = acc[s][t][r] + bv[t];
                ss[t] += yv;
                qq[t] = fmaf(yv, yv, qq[t]);
                y[(size_t)(me + r) * OC + t * 16 + col] = f2h(yv);
            }
        }
    }
#pragma unroll
    for (int t = 0; t < NT; ++t) {
        float s = ss[t], q = qq[t];
        s += __shfl_xor(s, 16); s += __shfl_xor(s, 32);
        q += __shfl_xor(q, 16); q += __shfl_xor(q, 32);
        if (quad == 0) { redS[wv][t * 16 + col] = s; redQ[wv][t * 16 + col] = q; }
    }
    __syncthreads();
    int t0 = threadIdx.x;
    float* sl = sums + (blockIdx.x & 7) * 256;
    if (t0 < OC)
        atomicAdd(&sl[t0], redS[0][t0] + redS[1][t0] + redS[2][t0] + redS[3][t0]);
    else if (t0 >= 128 && t0 < 128 + OC) {
        int c = t0 - 128;
        atomicAdd(&sl[128 + c], redQ[0][c] + redQ[1][c] + redQ[2][c] + redQ[3][c]);
    }
}

// Global average pool over y4 (512,24,24,128) f16 NHWC, BN4+ReLU applied.
__global__ __launch_bounds__(256) void pool(const ushort* __restrict__ y4,
                                            const float* __restrict__ ab,
                                            float* __restrict__ f)
{
    int n = blockIdx.x;
    int c = threadIdx.x & 127, ph = threadIdx.x >> 7;
    const ushort* p = y4 + (size_t)n * 73728 + c;
    float a = ab[c], b = ab[128 + c];
    float s = 0.f;
    for (int i = ph * 288; i < ph * 288 + 288; ++i) {
        _Float16 hv;
        __builtin_memcpy(&hv, p + i * 128, 2);
        s += fmaxf(fmaf(a, (float)hv, b), 0.f);
    }
    __shared__ float l[128];
    if (ph == 1) l[c] = s;
    __syncthreads();
    if (ph == 0) f[n * 128 + c] = (s + l[c]) * (1.f / 576.f);
}

// L2-normalize feature rows, emit f16.
__global__ __launch_bounds__(128) void fnorm(const float* __restrict__ f,
                                             ushort* __restrict__ fnh)
{
    int n = blockIdx.x, t = threadIdx.x;
    float v = f[n * 128 + t];
    float q = v * v;
    for (int off = 32; off; off >>= 1) q += __shfl_down(q, off);
    __shared__ float l[2];
    if ((t & 63) == 0) l[t >> 6] = q;
    __syncthreads();
    float inv = 1.f / fmaxf(sqrtf(l[0] + l[1]), 1e-12f);
    fnh[n * 128 + t] = f2h(v * inv);
}

// L2-normalize arc_w rows once, emit f16 rows [j][128]. One wave per row.
__global__ __launch_bounds__(256) void wpack(const float* __restrict__ w,
                                             ushort* __restrict__ w16)
{
    int wv = threadIdx.x >> 6, lane = threadIdx.x & 63;
    int j = blockIdx.x * 4 + wv;
    const float* p = w + (size_t)j * 128;
    float v0 = p[lane], v1 = p[lane + 64];
    float q = fmaf(v0, v0, v1 * v1);
#pragma unroll
    for (int off = 32; off; off >>= 1) q += __shfl_down(q, off);
    float inv = 1.f / fmaxf(sqrtf(__shfl(q, 0)), 1e-12f);
    w16[(size_t)j * 128 + lane]      = f2h(v0 * inv);
    w16[(size_t)j * 128 + lane + 64] = f2h(v1 * inv);
}

// ---------------------------------------------------------------------------
// Final GEMM: out[i][j] = 64 * (fn[i] . wn[j]), margin fix at j == gt[i].
// M=512, N=100000, K=128. Swapped-operand MFMA: mfma(w_frag, f_frag) puts
// 4 consecutive j in each lane's acc -> one f32x4 nontemporal store per mt.
// Weights pre-normalized f16 (wpack). 100000 % 16 == 0 -> wave-uniform tail.
// ---------------------------------------------------------------------------
__global__ __launch_bounds__(256) void arc_gemm(const ushort* __restrict__ fnh,
                                                const ushort* __restrict__ w16,
                                                const int* __restrict__ gt,
                                                float* __restrict__ out)
{
    const int lane = threadIdx.x & 63, wv = threadIdx.x >> 6;
    const int col = lane & 15, quad = lane >> 4;
    const int jbase = blockIdx.x * 64 + wv * 16;
    if (jbase >= 100000) return;

    // A-operand fragments: lane holds w16 row (jbase+col), k = quad*8 + s*32
    half8 bfr[4];
    const ushort* wp = w16 + (size_t)(jbase + col) * 128 + quad * 8;
#pragma unroll
    for (int s = 0; s < 4; ++s)
        __builtin_memcpy(&bfr[s], wp + s * 32, 16);

    const float cm = 0.87758256189037272f;  // cos(0.5)
    const float sm = 0.47942553860420301f;  // sin(0.5)
    const int j0 = jbase + quad * 4;

    half8 afA[4], afB[4];
    const ushort* ap0 = fnh + (size_t)col * 128 + quad * 8;
#pragma unroll
    for (int s = 0; s < 4; ++s)
        __builtin_memcpy(&afA[s], ap0 + s * 32, 16);

    auto step = [&](int mt, half8 (&cur)[4], half8 (&nxt)[4]) {
        if (mt + 1 < 32) {
            const ushort* apn = fnh + (size_t)((mt + 1) * 16 + col) * 128 + quad * 8;
#pragma unroll
            for (int s = 0; s < 4; ++s)
                __builtin_memcpy(&nxt[s], apn + s * 32, 16);
        }
        f32x4 acc = {0.f, 0.f, 0.f, 0.f};
#pragma unroll
        for (int s = 0; s < 4; ++s)
            acc = __builtin_amdgcn_mfma_f32_16x16x32_f16(bfr[s], cur[s], acc, 0, 0, 0);

        const int m = mt * 16 + col;
        const int d = gt[m] - j0;
        if ((uint)d < 4u) {
#pragma unroll
            for (int r = 0; r < 4; ++r)
                if (r == d) {
                    float v = acc[r];
                    float t = fmaxf(1.f - v * v, 0.f);
                    acc[r] = fmaf(v, cm, -sqrtf(t) * sm);
                }
        }
        f32x4 o4;
#pragma unroll
        for (int r = 0; r < 4; ++r) o4[r] = 64.f * acc[r];
        __builtin_nontemporal_store(o4, (f32x4*)(out + (size_t)m * 100000 + j0));
    };

    for (int mt = 0; mt < 32; mt += 2) {
        step(mt, afA, afB);
        step(mt + 1, afB, afA);
    }
}

// ---------------------------------------------------------------------------
extern "C" void kernel_launch(void* const* d_in, const int* in_sizes, int n_in,
                              void* d_out, int out_size, void* d_ws, size_t ws_size,
                              hipStream_t stream)
{
    const float* x   = (const float*)d_in[0];
    const int*   gt  = (const int*)d_in[1];
    const float* w1  = (const float*)d_in[2];
    const float* b1  = (const float*)d_in[3];
    const float* g1  = (const float*)d_in[4];
    const float* be1 = (const float*)d_in[5];
    const float* w2  = (const float*)d_in[6];
    const float* b2  = (const float*)d_in[7];
    const float* g2  = (const float*)d_in[8];
    const float* be2 = (const float*)d_in[9];
    const float* w3  = (const float*)d_in[10];
    const float* b3  = (const float*)d_in[11];
    const float* g3  = (const float*)d_in[12];
    const float* be3 = (const float*)d_in[13];
    const float* w4  = (const float*)d_in[14];
    const float* b4  = (const float*)d_in[15];
    const float* g4  = (const float*)d_in[16];
    const float* be4 = (const float*)d_in[17];
    const float* aw  = (const float*)d_in[18];
    float* out = (float*)d_out;

    float* ws = (float*)d_ws;
    // arena1: y1(12.85M f) -> y2(6.42M) -> y3(11.08M) -> y4(18.87M floats)
    ushort* yb  = (ushort*)ws;
    // arena2: h1(12.85M f) -> h2(6.42M) -> h3(11.08M floats); after conv4 the
    // arena is dead and is reused for w16 (100000 x 128 f16 = 6.4M floats).
    ushort* hb  = (ushort*)(ws + 18874368);
    ushort* w16 = hb;
    ushort* wb2 = (ushort*)(ws + 31719424);
    ushort* wb3 = (ushort*)(ws + 31723520);
    ushort* wb4 = (ushort*)(ws + 31732736);
    float* sums = ws + 31769600;   // 4 layers x 8 slots x 256
    float* ab   = ws + 31777792;   // 4 layers x 256
    float* fbuf = ws + 31778816;   // 512*128
    ushort* fnh = (ushort*)(ws + 31844352);  // 512*128 f16

    hipMemsetAsync(sums, 0, 4 * 2048 * sizeof(float), stream);

    // conv weight repacks (independent of conv chain)
    repack<32, 16, 4><<<32, 256, 0, stream>>>(w2, wb2);
    repack_cm<64, 32, 3><<<72, 256, 0, stream>>>(w3, wb3);
    repack_cm<128, 64, 3><<<288, 256, 0, stream>>>(w4, wb4);

    // conv1: (512,1,112,112) fp32 -> y1 (512,56,56,16) f16 NHWC
    conv1_k<<<6272, 256, 0, stream>>>(x, w1, b1, yb, sums);
    mkab<<<1, 128, 0, stream>>>(sums, g1, be1, ab, 16, 1.f / 1605632.f);
    fold<16><<<12544, 256, 0, stream>>>(yb, ab, hb);

    // conv2 -> y2 (512,28,28,32) f16 NHWC
    conv2_mfma<<<3136, 256, 0, stream>>>(hb, wb2, b2, yb, sums + 2048);
    mkab<<<1, 128, 0, stream>>>(sums + 2048, g2, be2, ab + 256, 32, 1.f / 401408.f);
    fold<32><<<6272, 256, 0, stream>>>(yb, ab + 256, hb);

    // conv3 -> y3 (512,26,26,64) f16 NHWC  (LDS-staged, chunk-major B)
    conv_lds<32, 64, 3, 28, 28, 26, 26><<<1352, 256, 0, stream>>>(hb, wb3, b3, yb, sums + 4096);
    mkab<<<1, 128, 0, stream>>>(sums + 4096, g3, be3, ab + 512, 64, 1.f / 346112.f);
    fold<64><<<10816, 256, 0, stream>>>(yb, ab + 512, hb);

    // conv4 -> y4 (512,24,24,128) f16 NHWC  (LDS-staged, chunk-major B)
    conv_lds<64, 128, 3, 26, 26, 24, 24><<<1152, 256, 0, stream>>>(hb, wb4, b4, yb, sums + 6144);
    mkab<<<1, 128, 0, stream>>>(sums + 6144, g4, be4, ab + 768, 128, 1.f / 294912.f);

    // hb arena is now dead: pack normalized f16 arc weights into it
    wpack<<<25000, 256, 0, stream>>>(aw, w16);

    // pool (applies BN4+ReLU) + feature normalize (f16)
    pool<<<512, 256, 0, stream>>>(yb, ab + 768, fbuf);
    fnorm<<<512, 128, 0, stream>>>(fbuf, fnh);

    // cosine logits + margin + scale
    arc_gemm<<<1563, 256, 0, stream>>>(fnh, w16, gt, out);
}

// Round 4
// 588.091 us; speedup vs baseline: 1.3308x; 1.0789x over previous
//
#include <hip/hip_runtime.h>

typedef unsigned int uint;
typedef unsigned short ushort;

typedef _Float16 half8 __attribute__((ext_vector_type(8)));
typedef float f32x4 __attribute__((ext_vector_type(4)));

#define DEV __device__ __forceinline__

DEV ushort f2h(float x) {
    _Float16 h = (_Float16)x;
    ushort u;
    __builtin_memcpy(&u, &h, 2);
    return u;
}

// ---------------------------------------------------------------------------
// conv1: direct fp32 VALU (IC=1, K too small for MFMA). One thread per output
// pixel, 16 oc in registers. Output y1: NHWC f16. Fused BN stats.
// ---------------------------------------------------------------------------
__global__ __launch_bounds__(256, 2) void conv1_k(
    const float* __restrict__ x, const float* __restrict__ w,
    const float* __restrict__ bias, ushort* __restrict__ y1,
    float* __restrict__ sums)
{
    int idx = blockIdx.x * 256 + threadIdx.x;
    int ow = idx % 56;
    int oh = (idx / 56) % 56;
    int n  = idx / 3136;

    float acc[16];
#pragma unroll
    for (int o = 0; o < 16; ++o) acc[o] = bias[o];

    const float* xp = x + (size_t)n * 12544;
#pragma unroll
    for (int kh = 0; kh < 4; ++kh) {
        int ih = oh * 2 - 1 + kh;
        if ((uint)ih >= 112u) continue;
#pragma unroll
        for (int kw = 0; kw < 4; ++kw) {
            int iw = ow * 2 - 1 + kw;
            if ((uint)iw >= 112u) continue;
            float v = xp[ih * 112 + iw];
#pragma unroll
            for (int o = 0; o < 16; ++o)
                acc[o] = fmaf(v, w[o * 16 + kh * 4 + kw], acc[o]);
        }
    }

    ushort hs[16];
#pragma unroll
    for (int o = 0; o < 16; ++o) hs[o] = f2h(acc[o]);
    __builtin_memcpy(y1 + (size_t)idx * 16, hs, 32);

    // fused BN stats
    __shared__ float red[2][4][16];
    int lane = threadIdx.x & 63, wv = threadIdx.x >> 6;
#pragma unroll
    for (int o = 0; o < 16; ++o) {
        float s = acc[o], q = acc[o] * acc[o];
#pragma unroll
        for (int off = 32; off; off >>= 1) {
            s += __shfl_down(s, off);
            q += __shfl_down(q, off);
        }
        if (lane == 0) { red[0][wv][o] = s; red[1][wv][o] = q; }
    }
    __syncthreads();
    float* sl = sums + (blockIdx.x & 7) * 256;
    int t = threadIdx.x;
    if (t < 16)
        atomicAdd(&sl[t], red[0][0][t] + red[0][1][t] + red[0][2][t] + red[0][3][t]);
    else if (t >= 64 && t < 80) {
        int o = t - 64;
        atomicAdd(&sl[128 + o], red[1][0][o] + red[1][1][o] + red[1][2][o] + red[1][3][o]);
    }
}

// sums (8 slots x 256) -> (a, b) fold:  h = relu(a*y + b)
__global__ __launch_bounds__(128) void mkab(const float* __restrict__ sums,
                                            const float* __restrict__ g,
                                            const float* __restrict__ be,
                                            float* __restrict__ ab, int C, float invP)
{
    int c = threadIdx.x;
    if (c >= C) return;
    float s = 0.f, q = 0.f;
#pragma unroll
    for (int k = 0; k < 8; ++k) { s += sums[k * 256 + c]; q += sums[k * 256 + 128 + c]; }
    float mu  = s * invP;
    float var = fmaf(-mu, mu, q * invP);
    float a   = g[c] / sqrtf(var + 1e-5f);
    ab[c]     = a;
    ab[C + c] = fmaf(-mu, a, be[c]);
}

// Elementwise fold: h = f16(relu(a*y + b)), NHWC, C = power of 2.
template <int C>
__global__ __launch_bounds__(256) void fold(const ushort* __restrict__ y,
                                            const float* __restrict__ ab,
                                            ushort* __restrict__ h)
{
    __shared__ float sa[C], sb[C];
    if (threadIdx.x < C) { sa[threadIdx.x] = ab[threadIdx.x]; sb[threadIdx.x] = ab[C + threadIdx.x]; }
    __syncthreads();
    int idx = blockIdx.x * 256 + threadIdx.x;
    half8 v;
    __builtin_memcpy(&v, y + (size_t)idx * 8, 16);
    int c0 = (idx * 8) & (C - 1);
    half8 o;
#pragma unroll
    for (int e = 0; e < 8; ++e) {
        float f = (float)v[e];
        o[e] = (_Float16)fmaxf(fmaf(sa[c0 + e], f, sb[c0 + e]), 0.f);
    }
    __builtin_memcpy(h + (size_t)idx * 8, &o, 16);
}

// conv2 weights OIHW fp32 -> chunk-major [q][oc][32] f16, q = kh*2 + kwp,
// element k in [0,32): kw = kwp*2 + (k>>4), ic = k&15.
__global__ __launch_bounds__(256) void repack_c2(const float* __restrict__ w,
                                                 ushort* __restrict__ wb)
{
    int i = blockIdx.x * 256 + threadIdx.x;   // 8192 total
    int e  = i & 31;
    int oc = (i >> 5) & 31;
    int q  = i >> 10;
    int kh = q >> 1, kwp = q & 1;
    int kw = kwp * 2 + (e >> 4);
    int ic = e & 15;
    wb[i] = f2h(w[((oc * 16 + ic) * 4 + kh) * 4 + kw]);
}

// Repack conv weights OIHW fp32 -> chunk-major [q][oc][32] f16, where
// q = (kh*K + kw)*(IC/32) + ic/32.
template <int OC, int IC, int K>
__global__ __launch_bounds__(256) void repack_cm(const float* __restrict__ w,
                                                 ushort* __restrict__ wb)
{
    constexpr int NC = IC / 32;
    int i = blockIdx.x * 256 + threadIdx.x;
    int e  = i & 31;
    int oc = (i >> 5) % OC;
    int q  = i / (32 * OC);
    int c  = q % NC;
    int r  = q / NC;
    int kw = r % K, kh = r / K;
    int ic = c * 32 + e;
    wb[i] = f2h(w[((oc * IC + ic) * K + kh) * K + kw]);
}

// ---------------------------------------------------------------------------
// conv2 (K=4, S=2, P=1, IC=16, OC=32): LDS-slab implicit GEMM. Block = 256 m.
// Input row range is contiguous in linear rows (padding rows resolve to
// neighbor-image rows already in the slab; masked at read). Chunk q=(kh,kwp):
// k = kwoff*16 + ic. Per-lane validity -> cndmask-zeroed fragment.
// ---------------------------------------------------------------------------
__global__ __launch_bounds__(256, 2) void conv2_lds(
    const ushort* __restrict__ hin, const ushort* __restrict__ wb,
    const float* __restrict__ bias, ushort* __restrict__ y,
    float* __restrict__ sums)
{
    constexpr int ROWB = 56 * 16 * 2;                       // 1792 B / input row
    constexpr int SLAB = ((24 * ROWB + 4095) / 4096) * 4096; // 45056 B
    __shared__ ushort slab[SLAB / 2];
    __shared__ float redS[4][32], redQ[4][32];

    const int lane = threadIdx.x & 63, wv = threadIdx.x >> 6;
    const int col = lane & 15, quad = lane >> 4;
    const int kwoff = quad >> 1;
    const int icoff = (quad & 1) * 8;
    const int mbase = blockIdx.x * 256 + wv * 64;

    const int m0 = blockIdx.x * 256;
    const int r0 = m0 / 28;                 // linear output row
    const int rL = (m0 + 255) / 28;
    const int rl0 = max(2 * r0 - 1, 0);
    const int rl1 = min(2 * rL + 2, 512 * 56 - 1);
    const int stage_bytes = (rl1 - rl0 + 1) * ROWB;

    // stage A slab: linear LDS dest, pre-swizzled global source
    {
        const char* src = (const char*)(hin + (size_t)rl0 * 896);
        char* dst = (char*)slab;
        int d = threadIdx.x * 16;
        int rounds = (stage_bytes + 4095) >> 12;
        for (int r = 0; r < rounds; ++r) {
            int sw = d ^ (((d >> 7) & 7) << 4);
            __builtin_amdgcn_global_load_lds(
                (const __attribute__((address_space(1))) void*)(src + sw),
                (__attribute__((address_space(3))) void*)(dst + d), 16, 0, 0);
            d += 4096;
        }
    }

    int nbase[4], ihb[4], iwb[4];
#pragma unroll
    for (int s = 0; s < 4; ++s) {
        int m = mbase + s * 16 + col;
        int n = m / 784, rem = m % 784;
        int oh = rem / 28, ow = rem % 28;
        nbase[s] = n * 56 - rl0;
        ihb[s] = oh * 2 - 1;
        iwb[s] = ow * 2 - 1 + kwoff;
    }
    const int bcol = col * 32 + quad * 8;

    f32x4 acc[4][2];
#pragma unroll
    for (int s = 0; s < 4; ++s)
#pragma unroll
        for (int t = 0; t < 2; ++t) acc[s][t] = (f32x4){0.f, 0.f, 0.f, 0.f};

    half8 bbuf[2][2];
#pragma unroll
    for (int t = 0; t < 2; ++t)
        __builtin_memcpy(&bbuf[0][t], wb + t * 512 + bcol, 16);

    __syncthreads();

#pragma unroll
    for (int q = 0; q < 8; ++q) {
        if (q + 1 < 8) {
            const ushort* bp = wb + (q + 1) * 1024 + bcol;
#pragma unroll
            for (int t = 0; t < 2; ++t)
                __builtin_memcpy(&bbuf[(q + 1) & 1][t], bp + t * 512, 16);
        }
        const int kh = q >> 1, kwp = q & 1;
#pragma unroll
        for (int s = 0; s < 4; ++s) {
            int ih = ihb[s] + kh;
            int iw = iwb[s] + kwp * 2;
            bool valid = ((uint)ih < 56u) && ((uint)iw < 56u);
            int off = valid ? ((nbase[s] + ih) * 896 + iw * 16 + icoff) : 0;
            int b = 2 * off;
            b ^= ((b >> 7) & 7) << 4;
            uint raw[4];
            __builtin_memcpy(raw, (const char*)slab + b, 16);
            if (!valid) { raw[0] = 0; raw[1] = 0; raw[2] = 0; raw[3] = 0; }
            half8 af;
            __builtin_memcpy(&af, raw, 16);
#pragma unroll
            for (int t = 0; t < 2; ++t)
                acc[s][t] = __builtin_amdgcn_mfma_f32_16x16x32_f16(af, bbuf[q & 1][t], acc[s][t], 0, 0, 0);
        }
    }

    // epilogue: bias, f16 store (NHWC), fused stats
    float bv[2];
#pragma unroll
    for (int t = 0; t < 2; ++t) bv[t] = bias[t * 16 + col];

    float ss[2] = {0.f, 0.f}, qq[2] = {0.f, 0.f};
#pragma unroll
    for (int s = 0; s < 4; ++s) {
        int me = mbase + s * 16 + quad * 4;
#pragma unroll
        for (int t = 0; t < 2; ++t) {
#pragma unroll
            for (int r = 0; r < 4; ++r) {
                float yv = acc[s][t][r] + bv[t];
                ss[t] += yv;
                qq[t] = fmaf(yv, yv, qq[t]);
                y[(size_t)(me + r) * 32 + t * 16 + col] = f2h(yv);
            }
        }
    }
#pragma unroll
    for (int t = 0; t < 2; ++t) {
        float s = ss[t], q = qq[t];
        s += __shfl_xor(s, 16); s += __shfl_xor(s, 32);
        q += __shfl_xor(q, 16); q += __shfl_xor(q, 32);
        if (quad == 0) { redS[wv][t * 16 + col] = s; redQ[wv][t * 16 + col] = q; }
    }
    __syncthreads();
    int t0 = threadIdx.x;
    float* sl = sums + (blockIdx.x & 7) * 256;
    if (t0 < 32)
        atomicAdd(&sl[t0], redS[0][t0] + redS[1][t0] + redS[2][t0] + redS[3][t0]);
    else if (t0 >= 128 && t0 < 160) {
        int c = t0 - 128;
        atomicAdd(&sl[128 + c], redQ[0][c] + redQ[1][c] + redQ[2][c] + redQ[3][c]);
    }
}

// ---------------------------------------------------------------------------
// conv3/conv4 (K=3, S=1, P=0): LDS-slab implicit GEMM, 256 m/block,
// chunk-major B register-double-buffered.
// ---------------------------------------------------------------------------
template <int IC, int OC, int K, int IH, int IW, int OH, int OW>
__global__ __launch_bounds__(256, 2) void conv_lds(
    const ushort* __restrict__ hin, const ushort* __restrict__ wb,
    const float* __restrict__ bias, ushort* __restrict__ y,
    float* __restrict__ sums)
{
    constexpr int NT  = OC / 16, NC = IC / 32;
    constexpr int NCH = K * K * NC;
    constexpr int ROWB = IW * IC * 2;                         // bytes / input row
    constexpr int MAXR = 255 / OW + K;                        // max rows spanned
    constexpr int SLAB = ((MAXR * ROWB + 4095) / 4096) * 4096;
    __shared__ ushort slab[SLAB / 2];
    __shared__ float redS[4][OC], redQ[4][OC];

    const int lane = threadIdx.x & 63, wv = threadIdx.x >> 6;
    const int col = lane & 15, quad = lane >> 4;
    const int mbase = blockIdx.x * 256 + wv * 64;

    const int m0  = blockIdx.x * 256;
    const int rl0 = (m0 / (OH * OW)) * IH + (m0 % (OH * OW)) / OW;
    const int mL  = m0 + 255;
    const int rl1 = (mL / (OH * OW)) * IH + (mL % (OH * OW)) / OW + (K - 1);
    const int stage_bytes = (rl1 - rl0 + 1) * ROWB;

    {
        const char* src = (const char*)(hin + (size_t)rl0 * (IW * IC));
        char* dst = (char*)slab;
        int d = threadIdx.x * 16;
        int rounds = (stage_bytes + 4095) >> 12;
        for (int r = 0; r < rounds; ++r) {
            int sw = d ^ (((d >> 7) & 7) << 4);
            __builtin_amdgcn_global_load_lds(
                (const __attribute__((address_space(1))) void*)(src + sw),
                (__attribute__((address_space(3))) void*)(dst + d), 16, 0, 0);
            d += 4096;
        }
    }

    int aloc[4];
#pragma unroll
    for (int s = 0; s < 4; ++s) {
        int m = mbase + s * 16 + col;
        int n = m / (OH * OW), rem = m % (OH * OW);
        int oh = rem / OW, ow = rem % OW;
        aloc[s] = ((n * IH + oh - rl0) * IW + ow) * IC + quad * 8;
    }
    const int bcol = col * 32 + quad * 8;

    f32x4 acc[4][NT];
#pragma unroll
    for (int s = 0; s < 4; ++s)
#pragma unroll
        for (int t = 0; t < NT; ++t) acc[s][t] = (f32x4){0.f, 0.f, 0.f, 0.f};

    half8 bbuf[2][NT];
#pragma unroll
    for (int t = 0; t < NT; ++t)
        __builtin_memcpy(&bbuf[0][t], wb + t * 512 + bcol, 16);

    __syncthreads();

#pragma unroll
    for (int q = 0; q < NCH; ++q) {
        if (q + 1 < NCH) {
            const ushort* bp = wb + (q + 1) * (OC * 32) + bcol;
#pragma unroll
            for (int t = 0; t < NT; ++t)
                __builtin_memcpy(&bbuf[(q + 1) & 1][t], bp + t * 512, 16);
        }
        const int kh = q / (K * NC), kw = (q / NC) % K, c = q % NC;
        const int aoff = (kh * IW + kw) * IC + c * 32;
#pragma unroll
        for (int s = 0; s < 4; ++s) {
            half8 af;
            int b = 2 * (aloc[s] + aoff);
            b ^= ((b >> 7) & 7) << 4;
            __builtin_memcpy(&af, (const char*)slab + b, 16);
#pragma unroll
            for (int t = 0; t < NT; ++t)
                acc[s][t] = __builtin_amdgcn_mfma_f32_16x16x32_f16(af, bbuf[q & 1][t], acc[s][t], 0, 0, 0);
        }
    }

    float bv[NT];
#pragma unroll
    for (int t = 0; t < NT; ++t) bv[t] = bias[t * 16 + col];

    float ss[NT], qq[NT];
#pragma unroll
    for (int t = 0; t < NT; ++t) { ss[t] = 0.f; qq[t] = 0.f; }
#pragma unroll
    for (int s = 0; s < 4; ++s) {
        int me = mbase + s * 16 + quad * 4;
#pragma unroll
        for (int t = 0; t < NT; ++t) {
#pragma unroll
            for (int r = 0; r < 4; ++r) {
                float yv = acc[s][t][r] + bv[t];
                ss[t] += yv;
                qq[t] = fmaf(yv, yv, qq[t]);
                y[(size_t)(me + r) * OC + t * 16 + col] = f2h(yv);
            }
        }
    }
#pragma unroll
    for (int t = 0; t < NT; ++t) {
        float s = ss[t], q = qq[t];
        s += __shfl_xor(s, 16); s += __shfl_xor(s, 32);
        q += __shfl_xor(q, 16); q += __shfl_xor(q, 32);
        if (quad == 0) { redS[wv][t * 16 + col] = s; redQ[wv][t * 16 + col] = q; }
    }
    __syncthreads();
    int t0 = threadIdx.x;
    float* sl = sums + (blockIdx.x & 7) * 256;
    if (t0 < OC)
        atomicAdd(&sl[t0], redS[0][t0] + redS[1][t0] + redS[2][t0] + redS[3][t0]);
    else if (t0 >= 128 && t0 < 128 + OC) {
        int c = t0 - 128;
        atomicAdd(&sl[128 + c], redQ[0][c] + redQ[1][c] + redQ[2][c] + redQ[3][c]);
    }
}

// Global average pool over y4 (512,24,24,128) f16 NHWC, BN4+ReLU applied.
// Vectorized: 16 c-groups x 16 pixel-phases, half8 loads, LDS reduce.
__global__ __launch_bounds__(256) void pool(const ushort* __restrict__ y4,
                                            const float* __restrict__ ab,
                                            float* __restrict__ f)
{
    int n = blockIdx.x;
    int g = threadIdx.x & 15, ph = threadIdx.x >> 4;
    const ushort* p = y4 + (size_t)n * 73728 + g * 8;
    float a8[8], b8[8];
#pragma unroll
    for (int e = 0; e < 8; ++e) { a8[e] = ab[g * 8 + e]; b8[e] = ab[128 + g * 8 + e]; }
    float s8[8];
#pragma unroll
    for (int e = 0; e < 8; ++e) s8[e] = 0.f;
    for (int i = ph; i < 576; i += 16) {
        half8 v;
        __builtin_memcpy(&v, p + i * 128, 16);
#pragma unroll
        for (int e = 0; e < 8; ++e)
            s8[e] += fmaxf(fmaf(a8[e], (float)v[e], b8[e]), 0.f);
    }
    __shared__ float l[16][128];
#pragma unroll
    for (int e = 0; e < 8; ++e) l[ph][g * 8 + e] = s8[e];
    __syncthreads();
    if (threadIdx.x < 128) {
        int c = threadIdx.x;
        float s = 0.f;
#pragma unroll
        for (int k = 0; k < 16; ++k) s += l[k][c];
        f[n * 128 + c] = s * (1.f / 576.f);
    }
}

// L2-normalize feature rows, emit f16.
__global__ __launch_bounds__(128) void fnorm(const float* __restrict__ f,
                                             ushort* __restrict__ fnh)
{
    int n = blockIdx.x, t = threadIdx.x;
    float v = f[n * 128 + t];
    float q = v * v;
    for (int off = 32; off; off >>= 1) q += __shfl_down(q, off);
    __shared__ float l[2];
    if ((t & 63) == 0) l[t >> 6] = q;
    __syncthreads();
    float inv = 1.f / fmaxf(sqrtf(l[0] + l[1]), 1e-12f);
    fnh[n * 128 + t] = f2h(v * inv);
}

// L2-normalize arc_w rows once, emit f16 rows [j][128]. One wave per row.
__global__ __launch_bounds__(256) void wpack(const float* __restrict__ w,
                                             ushort* __restrict__ w16)
{
    int wv = threadIdx.x >> 6, lane = threadIdx.x & 63;
    int j = blockIdx.x * 4 + wv;
    const float* p = w + (size_t)j * 128;
    float v0 = p[lane], v1 = p[lane + 64];
    float q = fmaf(v0, v0, v1 * v1);
#pragma unroll
    for (int off = 32; off; off >>= 1) q += __shfl_down(q, off);
    float inv = 1.f / fmaxf(sqrtf(__shfl(q, 0)), 1e-12f);
    w16[(size_t)j * 128 + lane]      = f2h(v0 * inv);
    w16[(size_t)j * 128 + lane + 64] = f2h(v1 * inv);
}

// ---------------------------------------------------------------------------
// Final GEMM: out[i][j] = 64 * (fn[i] . wn[j]), margin fix at j == gt[i].
// M=512, N=100000, K=128. Swapped-operand MFMA; wave handles 32 j (two
// A-fragments share each fnh B-fragment). f32x4 nontemporal stores.
// ---------------------------------------------------------------------------
__global__ __launch_bounds__(256) void arc_gemm(const ushort* __restrict__ fnh,
                                                const ushort* __restrict__ w16,
                                                const int* __restrict__ gt,
                                                float* __restrict__ out)
{
    const int lane = threadIdx.x & 63, wv = threadIdx.x >> 6;
    const int col = lane & 15, quad = lane >> 4;
    const int jbase = blockIdx.x * 128 + wv * 32;
    if (jbase >= 100000) return;

    half8 bfr[2][4];
#pragma unroll
    for (int jt = 0; jt < 2; ++jt) {
        const ushort* wp = w16 + (size_t)(jbase + jt * 16 + col) * 128 + quad * 8;
#pragma unroll
        for (int s = 0; s < 4; ++s)
            __builtin_memcpy(&bfr[jt][s], wp + s * 32, 16);
    }

    const float cm = 0.87758256189037272f;  // cos(0.5)
    const float sm = 0.47942553860420301f;  // sin(0.5)

    half8 afA[4], afB[4];
    const ushort* ap0 = fnh + (size_t)col * 128 + quad * 8;
#pragma unroll
    for (int s = 0; s < 4; ++s)
        __builtin_memcpy(&afA[s], ap0 + s * 32, 16);

    auto step = [&](int mt, half8 (&cur)[4], half8 (&nxt)[4]) {
        if (mt + 1 < 32) {
            const ushort* apn = fnh + (size_t)((mt + 1) * 16 + col) * 128 + quad * 8;
#pragma unroll
            for (int s = 0; s < 4; ++s)
                __builtin_memcpy(&nxt[s], apn + s * 32, 16);
        }
        f32x4 acc0 = {0.f, 0.f, 0.f, 0.f};
        f32x4 acc1 = {0.f, 0.f, 0.f, 0.f};
#pragma unroll
        for (int s = 0; s < 4; ++s) {
            acc0 = __builtin_amdgcn_mfma_f32_16x16x32_f16(bfr[0][s], cur[s], acc0, 0, 0, 0);
            acc1 = __builtin_amdgcn_mfma_f32_16x16x32_f16(bfr[1][s], cur[s], acc1, 0, 0, 0);
        }
        const int m = mt * 16 + col;
        const int g = gt[m];
#pragma unroll
        for (int jt = 0; jt < 2; ++jt) {
            f32x4& acc = jt ? acc1 : acc0;
            const int j0 = jbase + jt * 16 + quad * 4;
            const int d = g - j0;
            if ((uint)d < 4u) {
#pragma unroll
                for (int r = 0; r < 4; ++r)
                    if (r == d) {
                        float v = acc[r];
                        float t = fmaxf(1.f - v * v, 0.f);
                        acc[r] = fmaf(v, cm, -sqrtf(t) * sm);
                    }
            }
            f32x4 o4;
#pragma unroll
            for (int r = 0; r < 4; ++r) o4[r] = 64.f * acc[r];
            __builtin_nontemporal_store(o4, (f32x4*)(out + (size_t)m * 100000 + j0));
        }
    };

    for (int mt = 0; mt < 32; mt += 2) {
        step(mt, afA, afB);
        step(mt + 1, afB, afA);
    }
}

// ---------------------------------------------------------------------------
extern "C" void kernel_launch(void* const* d_in, const int* in_sizes, int n_in,
                              void* d_out, int out_size, void* d_ws, size_t ws_size,
                              hipStream_t stream)
{
    const float* x   = (const float*)d_in[0];
    const int*   gt  = (const int*)d_in[1];
    const float* w1  = (const float*)d_in[2];
    const float* b1  = (const float*)d_in[3];
    const float* g1  = (const float*)d_in[4];
    const float* be1 = (const float*)d_in[5];
    const float* w2  = (const float*)d_in[6];
    const float* b2  = (const float*)d_in[7];
    const float* g2  = (const float*)d_in[8];
    const float* be2 = (const float*)d_in[9];
    const float* w3  = (const float*)d_in[10];
    const float* b3  = (const float*)d_in[11];
    const float* g3  = (const float*)d_in[12];
    const float* be3 = (const float*)d_in[13];
    const float* w4  = (const float*)d_in[14];
    const float* b4  = (const float*)d_in[15];
    const float* g4  = (const float*)d_in[16];
    const float* be4 = (const float*)d_in[17];
    const float* aw  = (const float*)d_in[18];
    float* out = (float*)d_out;

    float* ws = (float*)d_ws;
    // arena1: y1(12.85M f) -> y2(6.42M) -> y3(11.08M) -> y4(18.87M floats)
    ushort* yb  = (ushort*)ws;
    // arena2: h1 -> h2 -> h3; dead after conv4, reused for w16 (100000x128 f16)
    ushort* hb  = (ushort*)(ws + 18874368);
    ushort* w16 = hb;
    ushort* wb2 = (ushort*)(ws + 31719424);
    ushort* wb3 = (ushort*)(ws + 31723520);
    ushort* wb4 = (ushort*)(ws + 31732736);
    float* sums = ws + 31769600;   // 4 layers x 8 slots x 256
    float* ab   = ws + 31777792;   // 4 layers x 256
    float* fbuf = ws + 31778816;   // 512*128
    ushort* fnh = (ushort*)(ws + 31844352);  // 512*128 f16

    hipMemsetAsync(sums, 0, 4 * 2048 * sizeof(float), stream);

    // conv weight repacks (independent of conv chain)
    repack_c2<<<32, 256, 0, stream>>>(w2, wb2);
    repack_cm<64, 32, 3><<<72, 256, 0, stream>>>(w3, wb3);
    repack_cm<128, 64, 3><<<288, 256, 0, stream>>>(w4, wb4);

    // conv1: (512,1,112,112) fp32 -> y1 (512,56,56,16) f16 NHWC
    conv1_k<<<6272, 256, 0, stream>>>(x, w1, b1, yb, sums);
    mkab<<<1, 128, 0, stream>>>(sums, g1, be1, ab, 16, 1.f / 1605632.f);
    fold<16><<<12544, 256, 0, stream>>>(yb, ab, hb);

    // conv2 -> y2 (512,28,28,32) f16 NHWC  (LDS-slab, chunk-major B)
    conv2_lds<<<1568, 256, 0, stream>>>(hb, wb2, b2, yb, sums + 2048);
    mkab<<<1, 128, 0, stream>>>(sums + 2048, g2, be2, ab + 256, 32, 1.f / 401408.f);
    fold<32><<<6272, 256, 0, stream>>>(yb, ab + 256, hb);

    // conv3 -> y3 (512,26,26,64) f16 NHWC  (LDS-slab, chunk-major B)
    conv_lds<32, 64, 3, 28, 28, 26, 26><<<1352, 256, 0, stream>>>(hb, wb3, b3, yb, sums + 4096);
    mkab<<<1, 128, 0, stream>>>(sums + 4096, g3, be3, ab + 512, 64, 1.f / 346112.f);
    fold<64><<<10816, 256, 0, stream>>>(yb, ab + 512, hb);

    // conv4 -> y4 (512,24,24,128) f16 NHWC  (LDS-slab, chunk-major B)
    conv_lds<64, 128, 3, 26, 26, 24, 24><<<1152, 256, 0, stream>>>(hb, wb4, b4, yb, sums + 6144);
    mkab<<<1, 128, 0, stream>>>(sums + 6144, g4, be4, ab + 768, 128, 1.f / 294912.f);

    // hb arena is now dead: pack normalized f16 arc weights into it
    wpack<<<25000, 256, 0, stream>>>(aw, w16);

    // pool (applies BN4+ReLU) + feature normalize (f16)
    pool<<<512, 256, 0, stream>>>(yb, ab + 768, fbuf);
    fnorm<<<512, 128, 0, stream>>>(fbuf, fnh);

    // cosine logits + margin + scale
    arc_gemm<<<782, 256, 0, stream>>>(fnh, w16, gt, out);
}

// Round 6
// 580.634 us; speedup vs baseline: 1.3479x; 1.0128x over previous
//
#include <hip/hip_runtime.h>

typedef unsigned int uint;
typedef unsigned short ushort;

typedef _Float16 half8 __attribute__((ext_vector_type(8)));
typedef float f32x4 __attribute__((ext_vector_type(4)));

#define DEV __device__ __forceinline__

DEV ushort f2h(float x) {
    _Float16 h = (_Float16)x;
    ushort u;
    __builtin_memcpy(&u, &h, 2);
    return u;
}

// ---------------------------------------------------------------------------
// conv1: direct fp32 VALU (IC=1). One thread per output pixel, 16 oc in regs.
// Output y1: NHWC f16. Fused BN stats.
// ---------------------------------------------------------------------------
__global__ __launch_bounds__(256, 2) void conv1_k(
    const float* __restrict__ x, const float* __restrict__ w,
    const float* __restrict__ bias, ushort* __restrict__ y1,
    float* __restrict__ sums)
{
    int idx = blockIdx.x * 256 + threadIdx.x;
    int ow = idx % 56;
    int oh = (idx / 56) % 56;
    int n  = idx / 3136;

    float acc[16];
#pragma unroll
    for (int o = 0; o < 16; ++o) acc[o] = bias[o];

    const float* xp = x + (size_t)n * 12544;
#pragma unroll
    for (int kh = 0; kh < 4; ++kh) {
        int ih = oh * 2 - 1 + kh;
        if ((uint)ih >= 112u) continue;
#pragma unroll
        for (int kw = 0; kw < 4; ++kw) {
            int iw = ow * 2 - 1 + kw;
            if ((uint)iw >= 112u) continue;
            float v = xp[ih * 112 + iw];
#pragma unroll
            for (int o = 0; o < 16; ++o)
                acc[o] = fmaf(v, w[o * 16 + kh * 4 + kw], acc[o]);
        }
    }

    ushort hs[16];
#pragma unroll
    for (int o = 0; o < 16; ++o) hs[o] = f2h(acc[o]);
    __builtin_memcpy(y1 + (size_t)idx * 16, hs, 32);

    // fused BN stats
    __shared__ float red[2][4][16];
    int lane = threadIdx.x & 63, wv = threadIdx.x >> 6;
#pragma unroll
    for (int o = 0; o < 16; ++o) {
        float s = acc[o], q = acc[o] * acc[o];
#pragma unroll
        for (int off = 32; off; off >>= 1) {
            s += __shfl_down(s, off);
            q += __shfl_down(q, off);
        }
        if (lane == 0) { red[0][wv][o] = s; red[1][wv][o] = q; }
    }
    __syncthreads();
    float* sl = sums + (blockIdx.x & 7) * 256;
    int t = threadIdx.x;
    if (t < 16)
        atomicAdd(&sl[t], red[0][0][t] + red[0][1][t] + red[0][2][t] + red[0][3][t]);
    else if (t >= 64 && t < 80) {
        int o = t - 64;
        atomicAdd(&sl[128 + o], red[1][0][o] + red[1][1][o] + red[1][2][o] + red[1][3][o]);
    }
}

// sums (8 slots x 256) -> (a, b) fold:  h = relu(a*y + b)
__global__ __launch_bounds__(128) void mkab(const float* __restrict__ sums,
                                            const float* __restrict__ g,
                                            const float* __restrict__ be,
                                            float* __restrict__ ab, int C, float invP)
{
    int c = threadIdx.x;
    if (c >= C) return;
    float s = 0.f, q = 0.f;
#pragma unroll
    for (int k = 0; k < 8; ++k) { s += sums[k * 256 + c]; q += sums[k * 256 + 128 + c]; }
    float mu  = s * invP;
    float var = fmaf(-mu, mu, q * invP);
    float a   = g[c] / sqrtf(var + 1e-5f);
    ab[c]     = a;
    ab[C + c] = fmaf(-mu, a, be[c]);
}

// Elementwise fold: h = f16(relu(a*y + b)), NHWC, C = power of 2.
template <int C>
__global__ __launch_bounds__(256) void fold(const ushort* __restrict__ y,
                                            const float* __restrict__ ab,
                                            ushort* __restrict__ h)
{
    __shared__ float sa[C], sb[C];
    if (threadIdx.x < C) { sa[threadIdx.x] = ab[threadIdx.x]; sb[threadIdx.x] = ab[C + threadIdx.x]; }
    __syncthreads();
    int idx = blockIdx.x * 256 + threadIdx.x;
    half8 v;
    __builtin_memcpy(&v, y + (size_t)idx * 8, 16);
    int c0 = (idx * 8) & (C - 1);
    half8 o;
#pragma unroll
    for (int e = 0; e < 8; ++e) {
        float f = (float)v[e];
        o[e] = (_Float16)fmaxf(fmaf(sa[c0 + e], f, sb[c0 + e]), 0.f);
    }
    __builtin_memcpy(h + (size_t)idx * 8, &o, 16);
}

// conv2 weights OIHW fp32 -> chunk-major [q][oc][32] f16, q = kh*2 + kwp,
// element k in [0,32): kw = kwp*2 + (k>>4), ic = k&15.
__global__ __launch_bounds__(256) void repack_c2(const float* __restrict__ w,
                                                 ushort* __restrict__ wb)
{
    int i = blockIdx.x * 256 + threadIdx.x;   // 8192 total
    int e  = i & 31;
    int oc = (i >> 5) & 31;
    int q  = i >> 10;
    int kh = q >> 1, kwp = q & 1;
    int kw = kwp * 2 + (e >> 4);
    int ic = e & 15;
    wb[i] = f2h(w[((oc * 16 + ic) * 4 + kh) * 4 + kw]);
}

// Repack conv weights OIHW fp32 -> chunk-major [q][oc][32] f16,
// q = (kh*K + kw)*(IC/32) + ic/32.
template <int OC, int IC, int K>
__global__ __launch_bounds__(256) void repack_cm(const float* __restrict__ w,
                                                 ushort* __restrict__ wb)
{
    constexpr int NC = IC / 32;
    int i = blockIdx.x * 256 + threadIdx.x;
    int e  = i & 31;
    int oc = (i >> 5) % OC;
    int q  = i / (32 * OC);
    int c  = q % NC;
    int r  = q / NC;
    int kw = r % K, kh = r / K;
    int ic = c * 32 + e;
    wb[i] = f2h(w[((oc * IC + ic) * K + kh) * K + kw]);
}

// ---------------------------------------------------------------------------
// conv2 (K=4,S=2,P=1,IC=16,OC=32): LDS-slab implicit GEMM, 256 m/block.
// Input h1 (post-BN). Padding taps zeroed at read.
// ---------------------------------------------------------------------------
__global__ __launch_bounds__(256, 2) void conv2_lds(
    const ushort* __restrict__ hin, const ushort* __restrict__ wb,
    const float* __restrict__ bias, ushort* __restrict__ y,
    float* __restrict__ sums)
{
    constexpr int ROWB = 56 * 16 * 2;                       // 1792 B / input row
    constexpr int SLAB = ((24 * ROWB + 4095) / 4096) * 4096; // 45056 B
    __shared__ ushort slab[SLAB / 2];
    __shared__ float redS[4][32], redQ[4][32];

    const int lane = threadIdx.x & 63, wv = threadIdx.x >> 6;
    const int col = lane & 15, quad = lane >> 4;
    const int kwoff = quad >> 1;
    const int icoff = (quad & 1) * 8;
    const int mbase = blockIdx.x * 256 + wv * 64;

    const int m0 = blockIdx.x * 256;
    const int r0 = m0 / 28;                 // linear output row
    const int rL = (m0 + 255) / 28;
    const int rl0 = max(2 * r0 - 1, 0);
    const int rl1 = min(2 * rL + 2, 512 * 56 - 1);
    const int stage_bytes = (rl1 - rl0 + 1) * ROWB;

    // stage A slab: linear LDS dest, pre-swizzled global source
    {
        const char* src = (const char*)(hin + (size_t)rl0 * 896);
        char* dst = (char*)slab;
        int d = threadIdx.x * 16;
        int rounds = (stage_bytes + 4095) >> 12;
        for (int r = 0; r < rounds; ++r) {
            int sw = d ^ (((d >> 7) & 7) << 4);
            __builtin_amdgcn_global_load_lds(
                (const __attribute__((address_space(1))) void*)(src + sw),
                (__attribute__((address_space(3))) void*)(dst + d), 16, 0, 0);
            d += 4096;
        }
    }

    int nbase[4], ihb[4], iwb[4];
#pragma unroll
    for (int s = 0; s < 4; ++s) {
        int m = mbase + s * 16 + col;
        int n = m / 784, rem = m % 784;
        int oh = rem / 28, ow = rem % 28;
        nbase[s] = n * 56 - rl0;
        ihb[s] = oh * 2 - 1;
        iwb[s] = ow * 2 - 1 + kwoff;
    }
    const int bcol = col * 32 + quad * 8;

    f32x4 acc[4][2];
#pragma unroll
    for (int s = 0; s < 4; ++s)
#pragma unroll
        for (int t = 0; t < 2; ++t) acc[s][t] = (f32x4){0.f, 0.f, 0.f, 0.f};

    half8 bbuf[2][2];
#pragma unroll
    for (int t = 0; t < 2; ++t)
        __builtin_memcpy(&bbuf[0][t], wb + t * 512 + bcol, 16);

    __syncthreads();

#pragma unroll
    for (int q = 0; q < 8; ++q) {
        if (q + 1 < 8) {
            const ushort* bp = wb + (q + 1) * 1024 + bcol;
#pragma unroll
            for (int t = 0; t < 2; ++t)
                __builtin_memcpy(&bbuf[(q + 1) & 1][t], bp + t * 512, 16);
        }
        const int kh = q >> 1, kwp = q & 1;
#pragma unroll
        for (int s = 0; s < 4; ++s) {
            int ih = ihb[s] + kh;
            int iw = iwb[s] + kwp * 2;
            bool valid = ((uint)ih < 56u) && ((uint)iw < 56u);
            int off = valid ? ((nbase[s] + ih) * 896 + iw * 16 + icoff) : 0;
            int b = 2 * off;
            b ^= ((b >> 7) & 7) << 4;
            uint raw[4];
            __builtin_memcpy(raw, (const char*)slab + b, 16);
            if (!valid) { raw[0] = 0; raw[1] = 0; raw[2] = 0; raw[3] = 0; }
            half8 af;
            __builtin_memcpy(&af, raw, 16);
#pragma unroll
            for (int t = 0; t < 2; ++t)
                acc[s][t] = __builtin_amdgcn_mfma_f32_16x16x32_f16(af, bbuf[q & 1][t], acc[s][t], 0, 0, 0);
        }
    }

    // epilogue: bias, f16 store (NHWC), fused stats
    float bv[2];
#pragma unroll
    for (int t = 0; t < 2; ++t) bv[t] = bias[t * 16 + col];

    float ss[2] = {0.f, 0.f}, qq[2] = {0.f, 0.f};
#pragma unroll
    for (int s = 0; s < 4; ++s) {
        int me = mbase + s * 16 + quad * 4;
#pragma unroll
        for (int t = 0; t < 2; ++t) {
#pragma unroll
            for (int r = 0; r < 4; ++r) {
                float yv = acc[s][t][r] + bv[t];
                ss[t] += yv;
                qq[t] = fmaf(yv, yv, qq[t]);
                y[(size_t)(me + r) * 32 + t * 16 + col] = f2h(yv);
            }
        }
    }
#pragma unroll
    for (int t = 0; t < 2; ++t) {
        float s = ss[t], q = qq[t];
        s += __shfl_xor(s, 16); s += __shfl_xor(s, 32);
        q += __shfl_xor(q, 16); q += __shfl_xor(q, 32);
        if (quad == 0) { redS[wv][t * 16 + col] = s; redQ[wv][t * 16 + col] = q; }
    }
    __syncthreads();
    int t0 = threadIdx.x;
    float* sl = sums + (blockIdx.x & 7) * 256;
    if (t0 < 32)
        atomicAdd(&sl[t0], redS[0][t0] + redS[1][t0] + redS[2][t0] + redS[3][t0]);
    else if (t0 >= 128 && t0 < 160) {
        int c = t0 - 128;
        atomicAdd(&sl[128 + c], redQ[0][c] + redQ[1][c] + redQ[2][c] + redQ[3][c]);
    }
}

// ---------------------------------------------------------------------------
// conv3/conv4 (K=3,S=1,P=0): LDS-slab implicit GEMM, 256 m/block, chunk-major
// B register-double-buffered.
// ---------------------------------------------------------------------------
template <int IC, int OC, int K, int IH, int IW, int OH, int OW>
__global__ __launch_bounds__(256, 2) void conv_lds(
    const ushort* __restrict__ hin, const ushort* __restrict__ wb,
    const float* __restrict__ bias, ushort* __restrict__ y,
    float* __restrict__ sums)
{
    constexpr int NT  = OC / 16, NC = IC / 32;
    constexpr int NCH = K * K * NC;
    constexpr int ROWB = IW * IC * 2;                         // bytes / input row
    constexpr int MAXR = 255 / OW + K;                        // max rows spanned
    constexpr int SLAB = ((MAXR * ROWB + 4095) / 4096) * 4096;
    __shared__ ushort slab[SLAB / 2];
    __shared__ float redS[4][OC], redQ[4][OC];

    const int lane = threadIdx.x & 63, wv = threadIdx.x >> 6;
    const int col = lane & 15, quad = lane >> 4;
    const int mbase = blockIdx.x * 256 + wv * 64;

    const int m0  = blockIdx.x * 256;
    const int rl0 = (m0 / (OH * OW)) * IH + (m0 % (OH * OW)) / OW;
    const int mL  = m0 + 255;
    const int rl1 = (mL / (OH * OW)) * IH + (mL % (OH * OW)) / OW + (K - 1);
    const int stage_bytes = (rl1 - rl0 + 1) * ROWB;

    {
        const char* src = (const char*)(hin + (size_t)rl0 * (IW * IC));
        char* dst = (char*)slab;
        int d = threadIdx.x * 16;
        int rounds = (stage_bytes + 4095) >> 12;
        for (int r = 0; r < rounds; ++r) {
            int sw = d ^ (((d >> 7) & 7) << 4);
            __builtin_amdgcn_global_load_lds(
                (const __attribute__((address_space(1))) void*)(src + sw),
                (__attribute__((address_space(3))) void*)(dst + d), 16, 0, 0);
            d += 4096;
        }
    }

    int aloc[4];
#pragma unroll
    for (int s = 0; s < 4; ++s) {
        int m = mbase + s * 16 + col;
        int n = m / (OH * OW), rem = m % (OH * OW);
        int oh = rem / OW, ow = rem % OW;
        aloc[s] = ((n * IH + oh - rl0) * IW + ow) * IC + quad * 8;
    }
    const int bcol = col * 32 + quad * 8;

    f32x4 acc[4][NT];
#pragma unroll
    for (int s = 0; s < 4; ++s)
#pragma unroll
        for (int t = 0; t < NT; ++t) acc[s][t] = (f32x4){0.f, 0.f, 0.f, 0.f};

    half8 bbuf[2][NT];
#pragma unroll
    for (int t = 0; t < NT; ++t)
        __builtin_memcpy(&bbuf[0][t], wb + t * 512 + bcol, 16);

    __syncthreads();

#pragma unroll
    for (int q = 0; q < NCH; ++q) {
        if (q + 1 < NCH) {
            const ushort* bp = wb + (q + 1) * (OC * 32) + bcol;
#pragma unroll
            for (int t = 0; t < NT; ++t)
                __builtin_memcpy(&bbuf[(q + 1) & 1][t], bp + t * 512, 16);
        }
        const int kh = q / (K * NC), kw = (q / NC) % K, c = q % NC;
        const int aoff = (kh * IW + kw) * IC + c * 32;
#pragma unroll
        for (int s = 0; s < 4; ++s) {
            half8 af;
            int b = 2 * (aloc[s] + aoff);
            b ^= ((b >> 7) & 7) << 4;
            __builtin_memcpy(&af, (const char*)slab + b, 16);
#pragma unroll
            for (int t = 0; t < NT; ++t)
                acc[s][t] = __builtin_amdgcn_mfma_f32_16x16x32_f16(af, bbuf[q & 1][t], acc[s][t], 0, 0, 0);
        }
    }

    float bv[NT];
#pragma unroll
    for (int t = 0; t < NT; ++t) bv[t] = bias[t * 16 + col];

    float ss[NT], qq[NT];
#pragma unroll
    for (int t = 0; t < NT; ++t) { ss[t] = 0.f; qq[t] = 0.f; }
#pragma unroll
    for (int s = 0; s < 4; ++s) {
        int me = mbase + s * 16 + quad * 4;
#pragma unroll
        for (int t = 0; t < NT; ++t) {
#pragma unroll
            for (int r = 0; r < 4; ++r) {
                float yv = acc[s][t][r] + bv[t];
                ss[t] += yv;
                qq[t] = fmaf(yv, yv, qq[t]);
                y[(size_t)(me + r) * OC + t * 16 + col] = f2h(yv);
            }
        }
    }
#pragma unroll
    for (int t = 0; t < NT; ++t) {
        float s = ss[t], q = qq[t];
        s += __shfl_xor(s, 16); s += __shfl_xor(s, 32);
        q += __shfl_xor(q, 16); q += __shfl_xor(q, 32);
        if (quad == 0) { redS[wv][t * 16 + col] = s; redQ[wv][t * 16 + col] = q; }
    }
    __syncthreads();
    int t0 = threadIdx.x;
    float* sl = sums + (blockIdx.x & 7) * 256;
    if (t0 < OC)
        atomicAdd(&sl[t0], redS[0][t0] + redS[1][t0] + redS[2][t0] + redS[3][t0]);
    else if (t0 >= 128 && t0 < 128 + OC) {
        int c = t0 - 128;
        atomicAdd(&sl[128 + c], redQ[0][c] + redQ[1][c] + redQ[2][c] + redQ[3][c]);
    }
}

// Global average pool over y4 (512,24,24,128) f16 NHWC, BN4+ReLU applied.
// Vectorized: 16 c-groups x 16 pixel-phases, half8 loads, LDS reduce.
__global__ __launch_bounds__(256) void pool(const ushort* __restrict__ y4,
                                            const float* __restrict__ ab,
                                            float* __restrict__ f)
{
    int n = blockIdx.x;
    int g = threadIdx.x & 15, ph = threadIdx.x >> 4;
    const ushort* p = y4 + (size_t)n * 73728 + g * 8;
    float a8[8], b8[8];
#pragma unroll
    for (int e = 0; e < 8; ++e) { a8[e] = ab[g * 8 + e]; b8[e] = ab[128 + g * 8 + e]; }
    float s8[8];
#pragma unroll
    for (int e = 0; e < 8; ++e) s8[e] = 0.f;
    for (int i = ph; i < 576; i += 16) {
        half8 v;
        __builtin_memcpy(&v, p + i * 128, 16);
#pragma unroll
        for (int e = 0; e < 8; ++e)
            s8[e] += fmaxf(fmaf(a8[e], (float)v[e], b8[e]), 0.f);
    }
    __shared__ float l[16][128];
#pragma unroll
    for (int e = 0; e < 8; ++e) l[ph][g * 8 + e] = s8[e];
    __syncthreads();
    if (threadIdx.x < 128) {
        int c = threadIdx.x;
        float s = 0.f;
#pragma unroll
        for (int k = 0; k < 16; ++k) s += l[k][c];
        f[n * 128 + c] = s * (1.f / 576.f);
    }
}

// L2-normalize feature rows, emit f16.
__global__ __launch_bounds__(128) void fnorm(const float* __restrict__ f,
                                             ushort* __restrict__ fnh)
{
    int n = blockIdx.x, t = threadIdx.x;
    float v = f[n * 128 + t];
    float q = v * v;
    for (int off = 32; off; off >>= 1) q += __shfl_down(q, off);
    __shared__ float l[2];
    if ((t & 63) == 0) l[t >> 6] = q;
    __syncthreads();
    float inv = 1.f / fmaxf(sqrtf(l[0] + l[1]), 1e-12f);
    fnh[n * 128 + t] = f2h(v * inv);
}

// L2-normalize arc_w rows once, emit f16 rows [j][128]. One wave per row.
__global__ __launch_bounds__(256) void wpack(const float* __restrict__ w,
                                             ushort* __restrict__ w16)
{
    int wv = threadIdx.x >> 6, lane = threadIdx.x & 63;
    int j = blockIdx.x * 4 + wv;
    const float* p = w + (size_t)j * 128;
    float v0 = p[lane], v1 = p[lane + 64];
    float q = fmaf(v0, v0, v1 * v1);
#pragma unroll
    for (int off = 32; off; off >>= 1) q += __shfl_down(q, off);
    float inv = 1.f / fmaxf(sqrtf(__shfl(q, 0)), 1e-12f);
    w16[(size_t)j * 128 + lane]      = f2h(v0 * inv);
    w16[(size_t)j * 128 + lane + 64] = f2h(v1 * inv);
}

// ---------------------------------------------------------------------------
// Final GEMM: out[i][j] = 64 * (fn[i] . wn[j]), margin fix at j == gt[i].
// M=512, N=100000, K=128. Swapped-operand MFMA; wave handles 64 j (four
// j-tiles share each fnh A-fragment). Tail tiles wave-uniform (100000%16==0).
// ---------------------------------------------------------------------------
__global__ __launch_bounds__(128) void arc_gemm(const ushort* __restrict__ fnh,
                                                const ushort* __restrict__ w16,
                                                const int* __restrict__ gt,
                                                float* __restrict__ out)
{
    const int lane = threadIdx.x & 63, wv = threadIdx.x >> 6;
    const int col = lane & 15, quad = lane >> 4;
    const int jbase = blockIdx.x * 128 + wv * 64;

    bool jv[4];
    half8 bfr[4][4];
#pragma unroll
    for (int jt = 0; jt < 4; ++jt) {
        int jr = jbase + jt * 16;
        jv[jt] = jr < 100000;
        int jc = jv[jt] ? jr + col : 99999;
        const ushort* wp = w16 + (size_t)jc * 128 + quad * 8;
#pragma unroll
        for (int s = 0; s < 4; ++s)
            __builtin_memcpy(&bfr[jt][s], wp + s * 32, 16);
    }

    const float cm = 0.87758256189037272f;  // cos(0.5)
    const float sm = 0.47942553860420301f;  // sin(0.5)

    half8 afA[4], afB[4];
    const ushort* ap0 = fnh + (size_t)col * 128 + quad * 8;
#pragma unroll
    for (int s = 0; s < 4; ++s)
        __builtin_memcpy(&afA[s], ap0 + s * 32, 16);

    auto step = [&](int mt, half8 (&cur)[4], half8 (&nxt)[4]) {
        if (mt + 1 < 32) {
            const ushort* apn = fnh + (size_t)((mt + 1) * 16 + col) * 128 + quad * 8;
#pragma unroll
            for (int s = 0; s < 4; ++s)
                __builtin_memcpy(&nxt[s], apn + s * 32, 16);
        }
        f32x4 acc[4];
#pragma unroll
        for (int jt = 0; jt < 4; ++jt) acc[jt] = (f32x4){0.f, 0.f, 0.f, 0.f};
#pragma unroll
        for (int s = 0; s < 4; ++s)
#pragma unroll
            for (int jt = 0; jt < 4; ++jt)
                acc[jt] = __builtin_amdgcn_mfma_f32_16x16x32_f16(bfr[jt][s], cur[s], acc[jt], 0, 0, 0);

        const int m = mt * 16 + col;
        const int g = gt[m];
#pragma unroll
        for (int jt = 0; jt < 4; ++jt) {
            if (!jv[jt]) continue;
            const int j0 = jbase + jt * 16 + quad * 4;
            const int d = g - j0;
            if ((uint)d < 4u) {
#pragma unroll
                for (int r = 0; r < 4; ++r)
                    if (r == d) {
                        float v = acc[jt][r];
                        float t = fmaxf(1.f - v * v, 0.f);
                        acc[jt][r] = fmaf(v, cm, -sqrtf(t) * sm);
                    }
            }
            f32x4 o4;
#pragma unroll
            for (int r = 0; r < 4; ++r) o4[r] = 64.f * acc[jt][r];
            __builtin_nontemporal_store(o4, (f32x4*)(out + (size_t)m * 100000 + j0));
        }
    };

    for (int mt = 0; mt < 32; mt += 2) {
        step(mt, afA, afB);
        step(mt + 1, afB, afA);
    }
}

// ---------------------------------------------------------------------------
extern "C" void kernel_launch(void* const* d_in, const int* in_sizes, int n_in,
                              void* d_out, int out_size, void* d_ws, size_t ws_size,
                              hipStream_t stream)
{
    const float* x   = (const float*)d_in[0];
    const int*   gt  = (const int*)d_in[1];
    const float* w1  = (const float*)d_in[2];
    const float* b1  = (const float*)d_in[3];
    const float* g1  = (const float*)d_in[4];
    const float* be1 = (const float*)d_in[5];
    const float* w2  = (const float*)d_in[6];
    const float* b2  = (const float*)d_in[7];
    const float* g2  = (const float*)d_in[8];
    const float* be2 = (const float*)d_in[9];
    const float* w3  = (const float*)d_in[10];
    const float* b3  = (const float*)d_in[11];
    const float* g3  = (const float*)d_in[12];
    const float* be3 = (const float*)d_in[13];
    const float* w4  = (const float*)d_in[14];
    const float* b4  = (const float*)d_in[15];
    const float* g4  = (const float*)d_in[16];
    const float* be4 = (const float*)d_in[17];
    const float* aw  = (const float*)d_in[18];
    float* out = (float*)d_out;

    float* ws = (float*)d_ws;
    // arena1: y1 -> y2 -> y3 -> y4
    ushort* yb  = (ushort*)ws;
    // arena2: h1 -> h2 -> h3; dead after conv4, reused for w16 (100000x128 f16)
    ushort* hb  = (ushort*)(ws + 18874368);
    ushort* w16 = hb;
    ushort* wb2 = (ushort*)(ws + 31719424);
    ushort* wb3 = (ushort*)(ws + 31723520);
    ushort* wb4 = (ushort*)(ws + 31732736);
    float* sums = ws + 31769600;   // 4 layers x 8 slots x 256
    float* ab   = ws + 31777792;   // 4 layers x 256
    float* fbuf = ws + 31778816;   // 512*128
    ushort* fnh = (ushort*)(ws + 31844352);  // 512*128 f16

    hipMemsetAsync(sums, 0, 4 * 2048 * sizeof(float), stream);

    // conv weight repacks (independent of conv chain)
    repack_c2<<<32, 256, 0, stream>>>(w2, wb2);
    repack_cm<64, 32, 3><<<72, 256, 0, stream>>>(w3, wb3);
    repack_cm<128, 64, 3><<<288, 256, 0, stream>>>(w4, wb4);

    // conv1: (512,1,112,112) fp32 -> y1 (512,56,56,16) f16 NHWC
    conv1_k<<<6272, 256, 0, stream>>>(x, w1, b1, yb, sums);
    mkab<<<1, 128, 0, stream>>>(sums, g1, be1, ab, 16, 1.f / 1605632.f);
    fold<16><<<12544, 256, 0, stream>>>(yb, ab, hb);

    // conv2 -> y2 (512,28,28,32) f16 NHWC  (LDS-slab, chunk-major B)
    conv2_lds<<<1568, 256, 0, stream>>>(hb, wb2, b2, yb, sums + 2048);
    mkab<<<1, 128, 0, stream>>>(sums + 2048, g2, be2, ab + 256, 32, 1.f / 401408.f);
    fold<32><<<6272, 256, 0, stream>>>(yb, ab + 256, hb);

    // conv3 -> y3 (512,26,26,64) f16 NHWC  (LDS-slab, chunk-major B)
    conv_lds<32, 64, 3, 28, 28, 26, 26><<<1352, 256, 0, stream>>>(hb, wb3, b3, yb, sums + 4096);
    mkab<<<1, 128, 0, stream>>>(sums + 4096, g3, be3, ab + 512, 64, 1.f / 346112.f);
    fold<64><<<10816, 256, 0, stream>>>(yb, ab + 512, hb);

    // conv4 -> y4 (512,24,24,128) f16 NHWC  (LDS-slab, chunk-major B)
    conv_lds<64, 128, 3, 26, 26, 24, 24><<<1152, 256, 0, stream>>>(hb, wb4, b4, yb, sums + 6144);
    mkab<<<1, 128, 0, stream>>>(sums + 6144, g4, be4, ab + 768, 128, 1.f / 294912.f);

    // hb arena dead: pack normalized f16 arc weights into it
    wpack<<<25000, 256, 0, stream>>>(aw, w16);

    // pool (applies BN4+ReLU) + feature normalize (f16)
    pool<<<512, 256, 0, stream>>>(yb, ab + 768, fbuf);
    fnorm<<<512, 128, 0, stream>>>(fbuf, fnh);

    // cosine logits + margin + scale
    arc_gemm<<<782, 128, 0, stream>>>(fnh, w16, gt, out);
}